// Round 1
// baseline (3715.714 us; speedup 1.0000x reference)
//
#include <hip/hip_runtime.h>
#include <math.h>

#define NB 4
#define T 65536
#define TIN 8192
#define LL 256
#define KCL 6144   // per-layer kernel channels = 32*64*3

__device__ __forceinline__ float lrelu_f(float v) { return v >= 0.f ? v : 0.2f * v; }

// ---------------- ConvTranspose1d: (B,32,8192) -> (B,32,65536) ----------------
// stride=8, K=16, pad=4. out[b,o,t] = bias[o] + sum_i x[b,i,s0]*w[i,o,k0] + x[b,i,s0-1]*w[i,o,k0+8]
__global__ void convt_kernel(const float* __restrict__ x, const float* __restrict__ w,
                             const float* __restrict__ bias, float* __restrict__ out) {
    const int t = blockIdx.x * 256 + threadIdx.x;
    const int o = blockIdx.y;
    const int b = blockIdx.z;
    __shared__ float ws[32 * 16];
    for (int idx = threadIdx.x; idx < 512; idx += 256) {
        int i = idx >> 4, k = idx & 15;
        ws[idx] = w[i * 512 + o * 16 + k];   // w layout (in=32, out=32, K=16)
    }
    __syncthreads();
    const int tp = t + 4;
    const int k0 = tp & 7;
    const int s0 = tp >> 3;
    float acc = bias[o];
    const float* xb = x + (size_t)b * 32 * TIN;
    const bool ok0 = (s0 < TIN);
    const bool ok1 = (s0 >= 1);
    for (int i = 0; i < 32; ++i) {
        if (ok0) acc += xb[i * TIN + s0] * ws[i * 16 + k0];
        if (ok1) acc += xb[i * TIN + s0 - 1] * ws[i * 16 + k0 + 8];
    }
    out[((size_t)b * 32 + o) * T + t] = acc;
}

// ---------------- generic conv1d over L=256 ----------------
// in (B,Cin,256), w (Cout,Cin,K), out (B,Cout,256); Cout = gridDim.x.
// post: 0 = none, 1 = lrelu, 2 = lrelu + res (res has Cout channels)
__global__ void conv1d_L256(const float* __restrict__ in, const float* __restrict__ w,
                            const float* __restrict__ bias, const float* __restrict__ res,
                            float* __restrict__ out, int Cin, int K, int pad, int post) {
    const int oc = blockIdx.x;
    const int b  = blockIdx.y;
    const int l  = threadIdx.x;
    extern __shared__ float ws[];
    const int WK = Cin * K;
    for (int idx = threadIdx.x; idx < WK; idx += 256) ws[idx] = w[(size_t)oc * WK + idx];
    __syncthreads();
    const float* inb = in + (size_t)b * Cin * LL;
    float acc = bias[oc];
    for (int c = 0; c < Cin; ++c) {
        const float* ic = inb + c * LL;
        for (int k = 0; k < K; ++k) {
            int p = l + k - pad;
            if (p >= 0 && p < LL) acc += ic[p] * ws[c * K + k];
        }
    }
    if (post >= 1) acc = lrelu_f(acc);
    const size_t oidx = ((size_t)b * gridDim.x + oc) * LL + l;
    if (post == 2) acc += res[oidx];
    out[oidx] = acc;
}

// ---------------- dilated conv 32->32 K=3 with lrelu on input and output ----------------
__global__ void dilated_conv(const float* __restrict__ h, const float* __restrict__ w,
                             const float* __restrict__ bias, float* __restrict__ y, int dil) {
    const int t = blockIdx.x * 256 + threadIdx.x;
    const int o = blockIdx.y;
    const int b = blockIdx.z;
    __shared__ float ws[96];
    if (threadIdx.x < 96) ws[threadIdx.x] = w[o * 96 + threadIdx.x];
    __syncthreads();
    const float* hb = h + (size_t)b * 32 * T;
    float acc = bias[o];
    for (int c = 0; c < 32; ++c) {
        const float* hc = hb + (size_t)c * T;
#pragma unroll
        for (int k = 0; k < 3; ++k) {
            int p = t + (k - 1) * dil;
            if (p >= 0 && p < T) {
                acc += lrelu_f(hc[p]) * ws[c * 3 + k];
            }
        }
    }
    y[((size_t)b * 32 + o) * T + t] = lrelu_f(acc);
}

// ---------------- LVC + gated activation + residual (in-place on h) ----------------
// block = (l, b); thread = s. o[oc,s] = bias + sum_{c,k} y[b,c,l*256+s+k-1] * K[b,c,oc,k,l]
// then h[b,j,t] = sigmoid(o[j]) * tanh(o[j+32]) + h[b,j,t]
__global__ void __launch_bounds__(256) lvc_kernel(const float* __restrict__ y,
                                                  const float* __restrict__ kh,
                                                  const float* __restrict__ bh,
                                                  float* __restrict__ h, int layer) {
    const int l = blockIdx.x;
    const int b = blockIdx.y;
    const int s = threadIdx.x;
    __shared__ float ks[KCL];        // relaid to [c][k][oc]
    __shared__ float xs[32 * 258];
    __shared__ float bs[64];

    // kernel slice: kh layout (B, 6144, 256), cc = (c*64+oc)*3+k
    for (int cc = threadIdx.x; cc < KCL; cc += 256) {
        int c   = cc / 192;
        int rem = cc - c * 192;
        int oc  = rem / 3;
        int k   = rem - oc * 3;
        ks[(c * 3 + k) * 64 + oc] = kh[((size_t)b * KCL + cc) * LL + l];
    }
    // x slice with halo: xs[c][j] = y[b,c, l*256 - 1 + j], j in [0,258)
    const int base = l * 256 - 1;
    for (int idx = threadIdx.x; idx < 32 * 258; idx += 256) {
        int c = idx / 258, j = idx - c * 258;
        int p = base + j;
        xs[idx] = (p >= 0 && p < T) ? y[((size_t)b * 32 + c) * T + p] : 0.f;
    }
    if (threadIdx.x < 64)
        bs[threadIdx.x] = bh[((size_t)b * 256 + layer * 64 + threadIdx.x) * LL + l];
    __syncthreads();

    float acc[64];
#pragma unroll
    for (int oc = 0; oc < 64; ++oc) acc[oc] = bs[oc];

    for (int c = 0; c < 32; ++c) {
        float x0 = xs[c * 258 + s];
        float x1 = xs[c * 258 + s + 1];
        float x2 = xs[c * 258 + s + 2];
        const float* k0p = ks + (c * 3 + 0) * 64;
        const float* k1p = ks + (c * 3 + 1) * 64;
        const float* k2p = ks + (c * 3 + 2) * 64;
#pragma unroll
        for (int oc = 0; oc < 64; ++oc) {
            acc[oc] += x0 * k0p[oc] + x1 * k1p[oc] + x2 * k2p[oc];
        }
    }

    const int t = l * 256 + s;
#pragma unroll
    for (int j = 0; j < 32; ++j) {
        float a  = acc[j];
        float g  = acc[j + 32];
        float sg = 1.f / (1.f + __expf(-a));
        float th = tanhf(g);
        size_t idx = ((size_t)b * 32 + j) * T + t;
        h[idx] = sg * th + h[idx];
    }
}

extern "C" void kernel_launch(void* const* d_in, const int* in_sizes, int n_in,
                              void* d_out, int out_size, void* d_ws, size_t ws_size,
                              hipStream_t stream) {
    const float* hidden  = (const float*)d_in[0];
    const float* spec    = (const float*)d_in[1];
    const float* convt_w = (const float*)d_in[2];
    const float* convt_b = (const float*)d_in[3];
    const float* kp_in_w = (const float*)d_in[4];
    const float* kp_in_b = (const float*)d_in[5];
    const float* rb_w1   = (const float*)d_in[6];
    const float* rb_b1   = (const float*)d_in[7];
    const float* rb_w2   = (const float*)d_in[8];
    const float* rb_b2   = (const float*)d_in[9];
    const float* kern_w  = (const float*)d_in[10];
    const float* kern_b  = (const float*)d_in[11];
    const float* bias_w  = (const float*)d_in[12];
    const float* bias_b  = (const float*)d_in[13];
    const float* lvc_w   = (const float*)d_in[14];
    const float* lvc_b   = (const float*)d_in[15];

    float* h  = (float*)d_out;              // running h, (4,32,65536)
    float* wsp = (float*)d_ws;
    float* y        = wsp;                          // B*32*T        = 8,388,608 f
    float* kh_layer = y + (size_t)NB * 32 * T;      // B*6144*256    = 6,291,456 f
    float* bh       = kh_layer + (size_t)NB * KCL * LL; // B*256*256 =   262,144 f
    float* kp_h     = bh + (size_t)NB * 256 * LL;   // B*64*256
    float* kp_tmp   = kp_h + (size_t)NB * 64 * LL;  // B*64*256

    // 1) conv transpose into h
    convt_kernel<<<dim3(T / 256, 32, NB), 256, 0, stream>>>(hidden, convt_w, convt_b, h);

    // 2) kernel predictor trunk
    conv1d_L256<<<dim3(64, NB), 256, 100 * 5 * 4, stream>>>(spec, kp_in_w, kp_in_b, nullptr,
                                                            kp_h, 100, 5, 2, 0);
    for (int i = 0; i < 3; ++i) {
        conv1d_L256<<<dim3(64, NB), 256, 64 * 3 * 4, stream>>>(
            kp_h, rb_w1 + (size_t)i * 64 * 64 * 3, rb_b1 + i * 64, nullptr, kp_tmp, 64, 3, 1, 1);
        conv1d_L256<<<dim3(64, NB), 256, 64 * 3 * 4, stream>>>(
            kp_tmp, rb_w2 + (size_t)i * 64 * 64 * 3, rb_b2 + i * 64, kp_h, kp_h, 64, 3, 1, 2);
    }
    // bias head: all 4 layers at once, (B,256,256)
    conv1d_L256<<<dim3(256, NB), 256, 64 * 3 * 4, stream>>>(kp_h, bias_w, bias_b, nullptr,
                                                            bh, 64, 3, 1, 0);

    static const int dil[4] = {1, 3, 9, 27};
    for (int layer = 0; layer < 4; ++layer) {
        // kern head slice for this layer: (B, 6144, 256)
        conv1d_L256<<<dim3(KCL, NB), 256, 64 * 3 * 4, stream>>>(
            kp_h, kern_w + (size_t)layer * KCL * 64 * 3, kern_b + layer * KCL, nullptr,
            kh_layer, 64, 3, 1, 0);
        // y = lrelu(conv_dil(lrelu(h)))
        dilated_conv<<<dim3(T / 256, 32, NB), 256, 0, stream>>>(
            h, lvc_w + (size_t)layer * 32 * 32 * 3, lvc_b + layer * 32, y, dil[layer]);
        // h = sigmoid(o[:32]) * tanh(o[32:]) + h
        lvc_kernel<<<dim3(LL, NB), 256, 0, stream>>>(y, kh_layer, bh, h, layer);
    }
}

// Round 2
// 1636.693 us; speedup vs baseline: 2.2703x; 2.2703x over previous
//
#include <hip/hip_runtime.h>
#include <math.h>

#define NB 4
#define T 65536
#define TIN 8192
#define LL 256
#define KCL 6144   // per-layer kernel channels = 32*64*3

__device__ __forceinline__ float lrelu_f(float v) { return v >= 0.f ? v : 0.2f * v; }

// ---------------- ConvTranspose1d: (B,32,8192) -> (B,32,65536) ----------------
// stride=8, K=16, pad=4. out[b,o,t] = bias[o] + sum_i x[b,i,s0]*w[i,o,k0] + x[b,i,s0-1]*w[i,o,k0+8]
__global__ void convt_kernel(const float* __restrict__ x, const float* __restrict__ w,
                             const float* __restrict__ bias, float* __restrict__ out) {
    const int t = blockIdx.x * 256 + threadIdx.x;
    const int o = blockIdx.y;
    const int b = blockIdx.z;
    __shared__ float ws[32 * 16];
    for (int idx = threadIdx.x; idx < 512; idx += 256) {
        int i = idx >> 4, k = idx & 15;
        ws[idx] = w[i * 512 + o * 16 + k];   // w layout (in=32, out=32, K=16)
    }
    __syncthreads();
    const int tp = t + 4;
    const int k0 = tp & 7;
    const int s0 = tp >> 3;
    float acc = bias[o];
    const float* xb = x + (size_t)b * 32 * TIN;
    const bool ok0 = (s0 < TIN);
    const bool ok1 = (s0 >= 1);
    for (int i = 0; i < 32; ++i) {
        if (ok0) acc += xb[i * TIN + s0] * ws[i * 16 + k0];
        if (ok1) acc += xb[i * TIN + s0 - 1] * ws[i * 16 + k0 + 8];
    }
    out[((size_t)b * 32 + o) * T + t] = acc;
}

// ---------------- generic conv1d over L=256 (small trunk convs only) ----------------
__global__ void conv1d_L256(const float* __restrict__ in, const float* __restrict__ w,
                            const float* __restrict__ bias, const float* __restrict__ res,
                            float* __restrict__ out, int Cin, int K, int pad, int post) {
    const int oc = blockIdx.x;
    const int b  = blockIdx.y;
    const int l  = threadIdx.x;
    extern __shared__ float ws[];
    const int WK = Cin * K;
    for (int idx = threadIdx.x; idx < WK; idx += 256) ws[idx] = w[(size_t)oc * WK + idx];
    __syncthreads();
    const float* inb = in + (size_t)b * Cin * LL;
    float acc = bias[oc];
    for (int c = 0; c < Cin; ++c) {
        const float* ic = inb + c * LL;
        for (int k = 0; k < K; ++k) {
            int p = l + k - pad;
            if (p >= 0 && p < LL) acc += ic[p] * ws[c * K + k];
        }
    }
    if (post >= 1) acc = lrelu_f(acc);
    const size_t oidx = ((size_t)b * gridDim.x + oc) * LL + l;
    if (post == 2) acc += res[oidx];
    out[oidx] = acc;
}

// ---------------- kern head GEMM: kh[b][l][m] = kb[ko] + sum_j W[ko][j]*X[b][j][l] ----------------
// m = ci*192 + kk*64 + oc  (ci in [0,32), kk in [0,3), oc in [0,64))
// ko = (ci*64+oc)*3 + kk ; j = hc*3 + t ; X[b][hc*3+t][l] = kp_h[b][hc][l+t-1] (zero pad)
// grid (192, NB): block handles 32 consecutive m (fixed ci,kk; oc0 in {0,32}), all 256 l.
__global__ void __launch_bounds__(256) kern_head(const float* __restrict__ kp_h,
                                                 const float* __restrict__ kw,
                                                 const float* __restrict__ kb,
                                                 float* __restrict__ kh, int layer) {
    const int b   = blockIdx.y;
    const int m0  = blockIdx.x * 32;
    const int ci  = m0 / 192;
    const int rem = m0 - ci * 192;
    const int kk  = rem >> 6;
    const int oc0 = rem & 63;
    const int s   = threadIdx.x;
    __shared__ float xs[32][258];

    float acc[32];
#pragma unroll
    for (int oc = 0; oc < 32; ++oc)
        acc[oc] = kb[layer * KCL + (ci * 64 + oc0 + oc) * 3 + kk];

    const float* wb = kw + (size_t)layer * KCL * 192;

    for (int half = 0; half < 2; ++half) {
        const int hc0 = half * 32;
        for (int idx = s; idx < 32 * 258; idx += 256) {
            int c = idx / 258, j = idx - c * 258;
            int p = j - 1;
            xs[c][j] = (p >= 0 && p < LL) ? kp_h[((size_t)b * 64 + hc0 + c) * LL + p] : 0.f;
        }
        __syncthreads();
        for (int c4 = 0; c4 < 8; ++c4) {
            float xv[12];
#pragma unroll
            for (int u = 0; u < 4; ++u) {
                xv[u * 3 + 0] = xs[c4 * 4 + u][s];
                xv[u * 3 + 1] = xs[c4 * 4 + u][s + 1];
                xv[u * 3 + 2] = xs[c4 * 4 + u][s + 2];
            }
            const int j0 = (hc0 + c4 * 4) * 3;
#pragma unroll
            for (int oc = 0; oc < 32; ++oc) {
                const float* wr = wb + (size_t)((ci * 64 + oc0 + oc) * 3 + kk) * 192 + j0;
#pragma unroll
                for (int u = 0; u < 12; ++u) acc[oc] += xv[u] * wr[u];
            }
        }
        __syncthreads();
    }

    float* op = kh + ((size_t)b * LL + s) * KCL + m0;
#pragma unroll
    for (int oc = 0; oc < 32; oc += 4)
        *(float4*)(op + oc) = make_float4(acc[oc], acc[oc + 1], acc[oc + 2], acc[oc + 3]);
}

// ---------------- dilated conv 32->32 K=3, lrelu on input and output, register-tiled ----------------
// grid (T/256, NB); block: all 32 oc for 256 t. Weights scalar (uniform).
__global__ void __launch_bounds__(256) dilated_conv(const float* __restrict__ h,
                                                    const float* __restrict__ w,
                                                    const float* __restrict__ bias,
                                                    float* __restrict__ y, int dil) {
    const int tb = blockIdx.x;
    const int b  = blockIdx.y;
    const int s  = threadIdx.x;
    const int t0 = tb * 256;
    const int W  = 256 + 2 * dil;
    __shared__ float xs[32][312];

    const float* hb = h + (size_t)b * 32 * T;
    for (int c = 0; c < 32; ++c) {
        for (int j = s; j < W; j += 256) {
            int p = t0 - dil + j;
            xs[c][j] = (p >= 0 && p < T) ? lrelu_f(hb[(size_t)c * T + p]) : 0.f;
        }
    }
    __syncthreads();

    float acc[32];
#pragma unroll
    for (int o = 0; o < 32; ++o) acc[o] = bias[o];

    for (int c = 0; c < 32; ++c) {
        float x0 = xs[c][s];
        float x1 = xs[c][s + dil];
        float x2 = xs[c][s + 2 * dil];
        const float* wc = w + c * 3;
#pragma unroll
        for (int o = 0; o < 32; ++o) {
            acc[o] += x0 * wc[o * 96 + 0] + x1 * wc[o * 96 + 1] + x2 * wc[o * 96 + 2];
        }
    }

    const int t = t0 + s;
#pragma unroll
    for (int o = 0; o < 32; ++o)
        y[((size_t)b * 32 + o) * T + t] = lrelu_f(acc[o]);
}

// ---------------- LVC + gated activation + residual (in-place on h) ----------------
// kh layout [b][l][m], m = ci*192 + kk*64 + oc (contiguous per block -> scalar loads)
__global__ void __launch_bounds__(256) lvc_kernel(const float* __restrict__ y,
                                                  const float* __restrict__ kh,
                                                  const float* __restrict__ bh,
                                                  float* __restrict__ h, int layer) {
    const int l = blockIdx.x;
    const int b = blockIdx.y;
    const int s = threadIdx.x;
    __shared__ float xs[32][258];

    // x slice with halo: xs[c][j] = y[b,c, l*256 - 1 + j], j in [0,258)
    const int base = l * 256 - 1;
    for (int idx = s; idx < 32 * 258; idx += 256) {
        int c = idx / 258, j = idx - c * 258;
        int p = base + j;
        xs[c][j] = (p >= 0 && p < T) ? y[((size_t)b * 32 + c) * T + p] : 0.f;
    }
    __syncthreads();

    float acc[64];
#pragma unroll
    for (int oc = 0; oc < 64; ++oc)
        acc[oc] = bh[((size_t)b * 256 + layer * 64 + oc) * LL + l];

    const float* kp = kh + ((size_t)b * LL + l) * KCL;   // uniform -> scalar loads
    for (int c = 0; c < 32; ++c) {
        float x0 = xs[c][s];
        float x1 = xs[c][s + 1];
        float x2 = xs[c][s + 2];
        const float* k0 = kp + c * 192;
#pragma unroll
        for (int oc = 0; oc < 64; ++oc) {
            acc[oc] += x0 * k0[oc] + x1 * k0[64 + oc] + x2 * k0[128 + oc];
        }
    }

    const int t = l * 256 + s;
#pragma unroll
    for (int j = 0; j < 32; ++j) {
        float a  = acc[j];
        float g  = acc[j + 32];
        float sg = 1.f / (1.f + __expf(-a));
        float th = tanhf(g);
        size_t idx = ((size_t)b * 32 + j) * T + t;
        h[idx] = sg * th + h[idx];
    }
}

extern "C" void kernel_launch(void* const* d_in, const int* in_sizes, int n_in,
                              void* d_out, int out_size, void* d_ws, size_t ws_size,
                              hipStream_t stream) {
    const float* hidden  = (const float*)d_in[0];
    const float* spec    = (const float*)d_in[1];
    const float* convt_w = (const float*)d_in[2];
    const float* convt_b = (const float*)d_in[3];
    const float* kp_in_w = (const float*)d_in[4];
    const float* kp_in_b = (const float*)d_in[5];
    const float* rb_w1   = (const float*)d_in[6];
    const float* rb_b1   = (const float*)d_in[7];
    const float* rb_w2   = (const float*)d_in[8];
    const float* rb_b2   = (const float*)d_in[9];
    const float* kern_w  = (const float*)d_in[10];
    const float* kern_b  = (const float*)d_in[11];
    const float* bias_w  = (const float*)d_in[12];
    const float* bias_b  = (const float*)d_in[13];
    const float* lvc_w   = (const float*)d_in[14];
    const float* lvc_b   = (const float*)d_in[15];

    float* h   = (float*)d_out;             // running h, (4,32,65536)
    float* wsp = (float*)d_ws;
    float* y        = wsp;                              // B*32*T     = 8,388,608 f
    float* kh_layer = y + (size_t)NB * 32 * T;          // B*256*6144 = 6,291,456 f  [b][l][m]
    float* bh       = kh_layer + (size_t)NB * LL * KCL; // B*256*256
    float* kp_h     = bh + (size_t)NB * 256 * LL;       // B*64*256
    float* kp_tmp   = kp_h + (size_t)NB * 64 * LL;      // B*64*256

    // 1) conv transpose into h
    convt_kernel<<<dim3(T / 256, 32, NB), 256, 0, stream>>>(hidden, convt_w, convt_b, h);

    // 2) kernel predictor trunk (tiny)
    conv1d_L256<<<dim3(64, NB), 256, 100 * 5 * 4, stream>>>(spec, kp_in_w, kp_in_b, nullptr,
                                                            kp_h, 100, 5, 2, 0);
    for (int i = 0; i < 3; ++i) {
        conv1d_L256<<<dim3(64, NB), 256, 64 * 3 * 4, stream>>>(
            kp_h, rb_w1 + (size_t)i * 64 * 64 * 3, rb_b1 + i * 64, nullptr, kp_tmp, 64, 3, 1, 1);
        conv1d_L256<<<dim3(64, NB), 256, 64 * 3 * 4, stream>>>(
            kp_tmp, rb_w2 + (size_t)i * 64 * 64 * 3, rb_b2 + i * 64, kp_h, kp_h, 64, 3, 1, 2);
    }
    // bias head: all 4 layers at once, (B,256,256)
    conv1d_L256<<<dim3(256, NB), 256, 64 * 3 * 4, stream>>>(kp_h, bias_w, bias_b, nullptr,
                                                            bh, 64, 3, 1, 0);

    static const int dil[4] = {1, 3, 9, 27};
    for (int layer = 0; layer < 4; ++layer) {
        // kern head slice for this layer -> kh_layer [b][l][6144]
        kern_head<<<dim3(192, NB), 256, 0, stream>>>(kp_h, kern_w, kern_b, kh_layer, layer);
        // y = lrelu(conv_dil(lrelu(h)))
        dilated_conv<<<dim3(T / 256, NB), 256, 0, stream>>>(
            h, lvc_w + (size_t)layer * 32 * 32 * 3, lvc_b + layer * 32, y, dil[layer]);
        // h = sigmoid(o[:32]) * tanh(o[32:]) + h
        lvc_kernel<<<dim3(LL, NB), 256, 0, stream>>>(y, kh_layer, bh, h, layer);
    }
}

// Round 3
// 1310.863 us; speedup vs baseline: 2.8346x; 1.2486x over previous
//
#include <hip/hip_runtime.h>
#include <math.h>

#define NB 4
#define T 65536
#define TIN 8192
#define LL 256
#define KCL 6144   // per-layer kernel channels = 32*64*3

__device__ __forceinline__ float lrelu_f(float v) { return v >= 0.f ? v : 0.2f * v; }

// ---------------- ConvTranspose1d as GEMM: OUT[(o,k0)][s0] ----------------
// out[b,o,t] = bias[o] + sum_i x[b,i,s0]*w[i,o,k0] + x[b,i,s0-1]*w[i,o,k0+8]
// t = s0*8 + k0 - 4. Block: 64 m (8 o x 8 k0) x 256 s0. grid (33, 4, NB).
__global__ void __launch_bounds__(256) convt_kernel(const float* __restrict__ x,
                                                    const float* __restrict__ w,
                                                    const float* __restrict__ bias,
                                                    float* __restrict__ out) {
    const int bx = blockIdx.x;
    const int mt = blockIdx.y;
    const int b  = blockIdx.z;
    const int tid = threadIdx.x;
    const int ts  = tid & 31;   // s0 sub-tile
    const int tm  = tid >> 5;   // o within tile
    const int o   = mt * 8 + tm;
    __shared__ float xs[32][257];
    __shared__ float wm[64][64];   // [i(tap,ch)][mm = o_local*8 + k0]
    const int s0base = bx * 256;

    const float* xb = x + (size_t)b * 32 * TIN;
    for (int idx = tid; idx < 32 * 257; idx += 256) {
        int c = idx / 257, j = idx - c * 257;
        int p = s0base - 1 + j;
        xs[c][j] = (p >= 0 && p < TIN) ? xb[c * TIN + p] : 0.f;
    }
    for (int idx = tid; idx < 4096; idx += 256) {
        int i = idx >> 6, mm = idx & 63;
        int oo = mt * 8 + (mm >> 3), k0 = mm & 7;
        wm[i][mm] = (i < 32) ? w[i * 512 + oo * 16 + k0]
                             : w[(i - 32) * 512 + oo * 16 + k0 + 8];
    }
    __syncthreads();

    const float bo = bias[o];
    float acc[8][8];   // [mi = k0][si]
#pragma unroll
    for (int mi = 0; mi < 8; ++mi)
#pragma unroll
        for (int si = 0; si < 8; ++si) acc[mi][si] = bo;

    for (int c = 0; c < 32; ++c) {
        float xv[9];
#pragma unroll
        for (int u = 0; u < 9; ++u) xv[u] = xs[c][ts * 8 + u];
        float w0[8], w1[8];
#pragma unroll
        for (int mi = 0; mi < 8; ++mi) { w0[mi] = wm[c][tm * 8 + mi]; w1[mi] = wm[32 + c][tm * 8 + mi]; }
#pragma unroll
        for (int mi = 0; mi < 8; ++mi)
#pragma unroll
            for (int si = 0; si < 8; ++si)
                acc[mi][si] += xv[si + 1] * w0[mi] + xv[si] * w1[mi];
    }

    const int tbase = s0base * 8 + ts * 64 - 4;
    float* ob = out + ((size_t)b * 32 + o) * T;
#pragma unroll
    for (int si = 0; si < 8; ++si) {
#pragma unroll
        for (int h2 = 0; h2 < 2; ++h2) {
            int t0 = tbase + si * 8 + h2 * 4;
            if (t0 >= 0 && t0 < T) {
                *(float4*)(ob + t0) = make_float4(acc[h2 * 4 + 0][si], acc[h2 * 4 + 1][si],
                                                  acc[h2 * 4 + 2][si], acc[h2 * 4 + 3][si]);
            }
        }
    }
}

// ---------------- generic conv1d over L=256 (small trunk convs only) ----------------
__global__ void conv1d_L256(const float* __restrict__ in, const float* __restrict__ w,
                            const float* __restrict__ bias, const float* __restrict__ res,
                            float* __restrict__ out, int Cin, int K, int pad, int post) {
    const int oc = blockIdx.x;
    const int b  = blockIdx.y;
    const int l  = threadIdx.x;
    extern __shared__ float ws[];
    const int WK = Cin * K;
    for (int idx = threadIdx.x; idx < WK; idx += 256) ws[idx] = w[(size_t)oc * WK + idx];
    __syncthreads();
    const float* inb = in + (size_t)b * Cin * LL;
    float acc = bias[oc];
    for (int c = 0; c < Cin; ++c) {
        const float* ic = inb + c * LL;
        for (int k = 0; k < K; ++k) {
            int p = l + k - pad;
            if (p >= 0 && p < LL) acc += ic[p] * ws[c * K + k];
        }
    }
    if (post >= 1) acc = lrelu_f(acc);
    const size_t oidx = ((size_t)b * gridDim.x + oc) * LL + l;
    if (post == 2) acc += res[oidx];
    out[oidx] = acc;
}

// ---------------- kern head GEMM, 2D register tile ----------------
// kh[b][l][m] (m = ci*192 + kk*64 + oc); grid (96, NB), bx -> (ci,kk), m0 = bx*64.
__global__ void __launch_bounds__(256) kern_head(const float* __restrict__ kp_h,
                                                 const float* __restrict__ kw,
                                                 const float* __restrict__ kb,
                                                 float* __restrict__ kh, int layer) {
    const int bx = blockIdx.x, b = blockIdx.y;
    const int ci = bx / 3, kk = bx - ci * 3;
    const int m0 = bx * 64;
    const int tid = threadIdx.x, ts = tid & 31, to = tid >> 5;
    __shared__ float xs[32][258];
    __shared__ float ws[96][64];   // [jj = c*3+t][oc]

    float acc[8][8];   // [oi][si]
#pragma unroll
    for (int oi = 0; oi < 8; ++oi) {
        float bv = kb[layer * KCL + (ci * 64 + to * 8 + oi) * 3 + kk];
#pragma unroll
        for (int si = 0; si < 8; ++si) acc[oi][si] = bv;
    }

    const float* wbase = kw + (size_t)layer * KCL * 192;
    for (int half = 0; half < 2; ++half) {
        const int hc0 = half * 32;
        __syncthreads();
        for (int idx = tid; idx < 32 * 258; idx += 256) {
            int c = idx / 258, j = idx - c * 258;
            int p = j - 1;
            xs[c][j] = (p >= 0 && p < LL) ? kp_h[((size_t)b * 64 + hc0 + c) * LL + p] : 0.f;
        }
        for (int idx = tid; idx < 6144; idx += 256) {
            int jj = idx >> 6, oc = idx & 63;
            ws[jj][oc] = wbase[(size_t)((ci * 64 + oc) * 3 + kk) * 192 + hc0 * 3 + jj];
        }
        __syncthreads();
        for (int c = 0; c < 32; ++c) {
            float xv[10];
#pragma unroll
            for (int u = 0; u < 10; ++u) xv[u] = xs[c][ts * 8 + u];
#pragma unroll
            for (int t = 0; t < 3; ++t) {
                float wv[8];
#pragma unroll
                for (int oi = 0; oi < 8; ++oi) wv[oi] = ws[c * 3 + t][to * 8 + oi];
#pragma unroll
                for (int oi = 0; oi < 8; ++oi)
#pragma unroll
                    for (int si = 0; si < 8; ++si)
                        acc[oi][si] += wv[oi] * xv[si + t];
            }
        }
    }

#pragma unroll
    for (int si = 0; si < 8; ++si) {
        int l = ts * 8 + si;
        float* op = kh + ((size_t)b * LL + l) * KCL + m0 + to * 8;
#pragma unroll
        for (int oi = 0; oi < 8; oi += 4)
            *(float4*)(op + oi) = make_float4(acc[oi][si], acc[oi + 1][si],
                                              acc[oi + 2][si], acc[oi + 3][si]);
    }
}

// ---------------- dilated conv 32->32 K=3, lrelu in/out, 2D register tile ----------------
__global__ void __launch_bounds__(256) dilated_conv(const float* __restrict__ hsrc,
                                                    const float* __restrict__ w,
                                                    const float* __restrict__ bias,
                                                    float* __restrict__ y, int dil) {
    const int tb = blockIdx.x, b = blockIdx.y;
    const int tid = threadIdx.x, ts = tid & 31, to = tid >> 5;
    const int t0 = tb * 256;
    const int W = 256 + 2 * dil;
    __shared__ float xs[32][310];
    __shared__ float ws[96][32];   // [c*3+k][oc]

    const float* hb = hsrc + (size_t)b * 32 * T;
    for (int idx = tid; idx < 32 * W; idx += 256) {
        int c = idx / W, j = idx - c * W;
        int p = t0 - dil + j;
        xs[c][j] = (p >= 0 && p < T) ? lrelu_f(hb[(size_t)c * T + p]) : 0.f;
    }
    for (int idx = tid; idx < 3072; idx += 256) {
        int ck = idx >> 5, oc = idx & 31;
        ws[ck][oc] = w[oc * 96 + ck];
    }
    __syncthreads();

    float acc[4][8];
#pragma unroll
    for (int j = 0; j < 4; ++j) {
        float bv = bias[to * 4 + j];
#pragma unroll
        for (int si = 0; si < 8; ++si) acc[j][si] = bv;
    }

    for (int c = 0; c < 32; ++c) {
#pragma unroll
        for (int k = 0; k < 3; ++k) {
            float x8[8];
#pragma unroll
            for (int si = 0; si < 8; ++si) x8[si] = xs[c][ts * 8 + si + k * dil];
            float w4[4];
#pragma unroll
            for (int j = 0; j < 4; ++j) w4[j] = ws[c * 3 + k][to * 4 + j];
#pragma unroll
            for (int j = 0; j < 4; ++j)
#pragma unroll
                for (int si = 0; si < 8; ++si)
                    acc[j][si] += w4[j] * x8[si];
        }
    }

#pragma unroll
    for (int j = 0; j < 4; ++j) {
        int oc = to * 4 + j;
        float* yp = y + ((size_t)b * 32 + oc) * T + t0 + ts * 8;
        *(float4*)(yp)     = make_float4(lrelu_f(acc[j][0]), lrelu_f(acc[j][1]),
                                         lrelu_f(acc[j][2]), lrelu_f(acc[j][3]));
        *(float4*)(yp + 4) = make_float4(lrelu_f(acc[j][4]), lrelu_f(acc[j][5]),
                                         lrelu_f(acc[j][6]), lrelu_f(acc[j][7]));
    }
}

// ---------------- LVC + gated activation + residual, 2D register tile ----------------
// thread owns 4 gate-pairs (a_oc = to*4+j, g_oc = a_oc+32) x 8 s.
__global__ void __launch_bounds__(256) lvc_kernel(const float* __restrict__ y,
                                                  const float* __restrict__ kh,
                                                  const float* __restrict__ bh,
                                                  float* __restrict__ h, int layer) {
    const int l = blockIdx.x, b = blockIdx.y;
    const int tid = threadIdx.x, ts = tid & 31, to = tid >> 5;
    __shared__ float xs[32][258];
    __shared__ float ks[KCL];      // flat [c][k][oc]

    const int base = l * 256 - 1;
    for (int idx = tid; idx < 32 * 258; idx += 256) {
        int c = idx / 258, j = idx - c * 258;
        int p = base + j;
        xs[c][j] = (p >= 0 && p < T) ? y[((size_t)b * 32 + c) * T + p] : 0.f;
    }
    {
        const float* kp = kh + ((size_t)b * LL + l) * KCL;
        for (int idx = tid; idx < KCL; idx += 256) ks[idx] = kp[idx];
    }
    __syncthreads();

    float acc_a[4][8], acc_g[4][8];
#pragma unroll
    for (int j = 0; j < 4; ++j) {
        float ba = bh[((size_t)b * 256 + layer * 64 + to * 4 + j) * LL + l];
        float bg = bh[((size_t)b * 256 + layer * 64 + 32 + to * 4 + j) * LL + l];
#pragma unroll
        for (int si = 0; si < 8; ++si) { acc_a[j][si] = ba; acc_g[j][si] = bg; }
    }

    for (int c = 0; c < 32; ++c) {
        float xv[10];
#pragma unroll
        for (int u = 0; u < 10; ++u) xv[u] = xs[c][ts * 8 + u];
#pragma unroll
        for (int k = 0; k < 3; ++k) {
            const float* kr = ks + (c * 3 + k) * 64;
            float wa[4], wg[4];
#pragma unroll
            for (int j = 0; j < 4; ++j) { wa[j] = kr[to * 4 + j]; wg[j] = kr[32 + to * 4 + j]; }
#pragma unroll
            for (int j = 0; j < 4; ++j)
#pragma unroll
                for (int si = 0; si < 8; ++si) {
                    acc_a[j][si] += wa[j] * xv[si + k];
                    acc_g[j][si] += wg[j] * xv[si + k];
                }
        }
    }

#pragma unroll
    for (int j = 0; j < 4; ++j) {
        int a_oc = to * 4 + j;
        float* hp = h + ((size_t)b * 32 + a_oc) * T + l * 256 + ts * 8;
#pragma unroll
        for (int half = 0; half < 2; ++half) {
            float4 hv = *(float4*)(hp + half * 4);
            float r[4];
#pragma unroll
            for (int q = 0; q < 4; ++q) {
                int si = half * 4 + q;
                float a = acc_a[j][si], g = acc_g[j][si];
                float sg = 1.f / (1.f + __expf(-a));
                float th = tanhf(g);
                r[q] = sg * th;
            }
            *(float4*)(hp + half * 4) = make_float4(hv.x + r[0], hv.y + r[1],
                                                    hv.z + r[2], hv.w + r[3]);
        }
    }
}

extern "C" void kernel_launch(void* const* d_in, const int* in_sizes, int n_in,
                              void* d_out, int out_size, void* d_ws, size_t ws_size,
                              hipStream_t stream) {
    const float* hidden  = (const float*)d_in[0];
    const float* spec    = (const float*)d_in[1];
    const float* convt_w = (const float*)d_in[2];
    const float* convt_b = (const float*)d_in[3];
    const float* kp_in_w = (const float*)d_in[4];
    const float* kp_in_b = (const float*)d_in[5];
    const float* rb_w1   = (const float*)d_in[6];
    const float* rb_b1   = (const float*)d_in[7];
    const float* rb_w2   = (const float*)d_in[8];
    const float* rb_b2   = (const float*)d_in[9];
    const float* kern_w  = (const float*)d_in[10];
    const float* kern_b  = (const float*)d_in[11];
    const float* bias_w  = (const float*)d_in[12];
    const float* bias_b  = (const float*)d_in[13];
    const float* lvc_w   = (const float*)d_in[14];
    const float* lvc_b   = (const float*)d_in[15];

    float* h   = (float*)d_out;             // running h, (4,32,65536)
    float* wsp = (float*)d_ws;
    float* y        = wsp;                              // B*32*T     = 8,388,608 f
    float* kh_layer = y + (size_t)NB * 32 * T;          // B*256*6144 = 6,291,456 f  [b][l][m]
    float* bh       = kh_layer + (size_t)NB * LL * KCL; // B*256*256
    float* kp_h     = bh + (size_t)NB * 256 * LL;       // B*64*256
    float* kp_tmp   = kp_h + (size_t)NB * 64 * LL;      // B*64*256

    // 1) conv transpose into h
    convt_kernel<<<dim3(33, 4, NB), 256, 0, stream>>>(hidden, convt_w, convt_b, h);

    // 2) kernel predictor trunk (tiny)
    conv1d_L256<<<dim3(64, NB), 256, 100 * 5 * 4, stream>>>(spec, kp_in_w, kp_in_b, nullptr,
                                                            kp_h, 100, 5, 2, 0);
    for (int i = 0; i < 3; ++i) {
        conv1d_L256<<<dim3(64, NB), 256, 64 * 3 * 4, stream>>>(
            kp_h, rb_w1 + (size_t)i * 64 * 64 * 3, rb_b1 + i * 64, nullptr, kp_tmp, 64, 3, 1, 1);
        conv1d_L256<<<dim3(64, NB), 256, 64 * 3 * 4, stream>>>(
            kp_tmp, rb_w2 + (size_t)i * 64 * 64 * 3, rb_b2 + i * 64, kp_h, kp_h, 64, 3, 1, 2);
    }
    // bias head: all 4 layers at once, (B,256,256)
    conv1d_L256<<<dim3(256, NB), 256, 64 * 3 * 4, stream>>>(kp_h, bias_w, bias_b, nullptr,
                                                            bh, 64, 3, 1, 0);

    static const int dil[4] = {1, 3, 9, 27};
    for (int layer = 0; layer < 4; ++layer) {
        kern_head<<<dim3(96, NB), 256, 0, stream>>>(kp_h, kern_w, kern_b, kh_layer, layer);
        dilated_conv<<<dim3(T / 256, NB), 256, 0, stream>>>(
            h, lvc_w + (size_t)layer * 32 * 32 * 3, lvc_b + layer * 32, y, dil[layer]);
        lvc_kernel<<<dim3(LL, NB), 256, 0, stream>>>(y, kh_layer, bh, h, layer);
    }
}

// Round 4
// 1018.167 us; speedup vs baseline: 3.6494x; 1.2875x over previous
//
#include <hip/hip_runtime.h>
#include <math.h>

#define NB 4
#define T 65536
#define TIN 8192
#define LL 256
#define KCL 6144   // per-layer kernel channels = 32*64*3

__device__ __forceinline__ float lrelu_f(float v) { return v >= 0.f ? v : 0.2f * v; }

// ---------------- ConvTranspose1d as GEMM ----------------
// out[b,o,t] = bias[o] + sum_i x[b,i,s0]*w[i,o,k0] + x[b,i,s0-1]*w[i,o,k0+8], t = s0*8+k0-4
// grid (33, 4, NB). Block: 8 o x 256 s0. Wave w owns o-pair {2w,2w+1}; lane owns s0 = lane+si*64.
__global__ void __launch_bounds__(256, 3) convt_kernel(const float* __restrict__ x,
                                                       const float* __restrict__ w,
                                                       const float* __restrict__ bias,
                                                       float* __restrict__ out) {
    const int bx = blockIdx.x, mt = blockIdx.y, b = blockIdx.z;
    const int tid = threadIdx.x;
    const int lane = tid & 63, wv = tid >> 6;
    const int s0base = bx * 256;
    __shared__ float xs[32][264];   // xs[c][j] = x[b,c, s0base + j - 4], cols 3..259
    __shared__ float wm[64][64];    // [i(tap,ch)][mm = o_local*8 + k0]

    const float* xb = x + (size_t)b * 32 * TIN;
    for (int idx = tid; idx < 32 * 64; idx += 256) {
        int c = idx >> 6, q = idx & 63;
        int p = s0base + q * 4;
        float4 v = (p + 3 < TIN) ? *(const float4*)(xb + c * TIN + p)
                                 : make_float4(0.f, 0.f, 0.f, 0.f);
        *(float4*)&xs[c][4 + 4 * q] = v;
    }
    if (tid < 32) {
        int p = s0base - 1;
        xs[tid][3] = (p >= 0) ? xb[tid * TIN + p] : 0.f;
    }
    for (int idx = tid; idx < 4096; idx += 256) {
        int i = idx >> 6, mm = idx & 63;
        int oo = mt * 8 + (mm >> 3), k0 = mm & 7;
        wm[i][mm] = (i < 32) ? w[i * 512 + oo * 16 + k0]
                             : w[(i - 32) * 512 + oo * 16 + k0 + 8];
    }
    __syncthreads();

    float acc[2][8][4];   // [ol][k0][si]
#pragma unroll
    for (int ol = 0; ol < 2; ++ol) {
        float bo = bias[mt * 8 + wv * 2 + ol];
#pragma unroll
        for (int k0 = 0; k0 < 8; ++k0)
#pragma unroll
            for (int si = 0; si < 4; ++si) acc[ol][k0][si] = bo;
    }

    for (int c = 0; c < 32; ++c) {
        float xm1[4], x0[4];
#pragma unroll
        for (int si = 0; si < 4; ++si) {
            xm1[si] = xs[c][lane + si * 64 + 3];   // x[s0-1]
            x0[si]  = xs[c][lane + si * 64 + 4];   // x[s0]
        }
        float w0[16], w1[16];
#pragma unroll
        for (int q = 0; q < 4; ++q) {
            *(float4*)&w0[q * 4] = *(const float4*)&wm[c][wv * 16 + q * 4];
            *(float4*)&w1[q * 4] = *(const float4*)&wm[32 + c][wv * 16 + q * 4];
        }
#pragma unroll
        for (int ol = 0; ol < 2; ++ol)
#pragma unroll
            for (int k0 = 0; k0 < 8; ++k0)
#pragma unroll
                for (int si = 0; si < 4; ++si)
                    acc[ol][k0][si] += x0[si] * w0[ol * 8 + k0] + xm1[si] * w1[ol * 8 + k0];
    }

#pragma unroll
    for (int ol = 0; ol < 2; ++ol) {
        float* ob = out + ((size_t)b * 32 + mt * 8 + wv * 2 + ol) * T;
#pragma unroll
        for (int si = 0; si < 4; ++si) {
            int tb = (s0base + lane + si * 64) * 8 - 4;
            if (tb >= 0 && tb < T)
                *(float4*)(ob + tb) = make_float4(acc[ol][0][si], acc[ol][1][si],
                                                  acc[ol][2][si], acc[ol][3][si]);
            if (tb + 4 >= 0 && tb + 4 < T)
                *(float4*)(ob + tb + 4) = make_float4(acc[ol][4][si], acc[ol][5][si],
                                                      acc[ol][6][si], acc[ol][7][si]);
        }
    }
}

// ---------------- generic conv1d over L=256 (small trunk convs only) ----------------
__global__ void conv1d_L256(const float* __restrict__ in, const float* __restrict__ w,
                            const float* __restrict__ bias, const float* __restrict__ res,
                            float* __restrict__ out, int Cin, int K, int pad, int post) {
    const int oc = blockIdx.x;
    const int b  = blockIdx.y;
    const int l  = threadIdx.x;
    extern __shared__ float ws[];
    const int WK = Cin * K;
    for (int idx = threadIdx.x; idx < WK; idx += 256) ws[idx] = w[(size_t)oc * WK + idx];
    __syncthreads();
    const float* inb = in + (size_t)b * Cin * LL;
    float acc = bias[oc];
    for (int c = 0; c < Cin; ++c) {
        const float* ic = inb + c * LL;
        for (int k = 0; k < K; ++k) {
            int p = l + k - pad;
            if (p >= 0 && p < LL) acc += ic[p] * ws[c * K + k];
        }
    }
    if (post >= 1) acc = lrelu_f(acc);
    const size_t oidx = ((size_t)b * gridDim.x + oc) * LL + l;
    if (post == 2) acc += res[oidx];
    out[oidx] = acc;
}

// ---------------- kern head GEMM ----------------
// kh[b][l][m], m = ci*192+kk*64+oc. grid (192, NB): bx -> (g = ci*3+kk, half of 32 oc).
// Wave w owns oc tile of 8; lane owns l = lane + si*64.
__global__ void __launch_bounds__(256, 3) kern_head(const float* __restrict__ kp_h,
                                                    const float* __restrict__ kw,
                                                    const float* __restrict__ kb,
                                                    float* __restrict__ kh, int layer) {
    const int bx = blockIdx.x, b = blockIdx.y;
    const int g = bx >> 1, oc0 = (bx & 1) * 32;
    const int ci = g / 3, kk = g - ci * 3;
    const int tid = threadIdx.x, lane = tid & 63, wv = tid >> 6;
    __shared__ float xs[32][264];   // xs[c][j] = X[hc0+c][j-4], cols 3..260 (3 and 260 are pad=0)
    __shared__ float ws[96][32];    // [jj = c*3+t][oc_local]

    float acc[8][4];
#pragma unroll
    for (int oi = 0; oi < 8; ++oi) {
        float bv = kb[layer * KCL + (ci * 64 + oc0 + wv * 8 + oi) * 3 + kk];
#pragma unroll
        for (int si = 0; si < 4; ++si) acc[oi][si] = bv;
    }

    const float* wbase = kw + (size_t)layer * KCL * 192;
    for (int half = 0; half < 2; ++half) {
        const int hc0 = half * 32;
        __syncthreads();
        for (int idx = tid; idx < 32 * 64; idx += 256) {
            int c = idx >> 6, q = idx & 63;
            *(float4*)&xs[c][4 + 4 * q] =
                *(const float4*)(kp_h + ((size_t)b * 64 + hc0 + c) * LL + 4 * q);
        }
        if (tid < 32) { xs[tid][3] = 0.f; xs[tid][260] = 0.f; }
        for (int idx = tid; idx < 3072; idx += 256) {
            int jj = idx >> 5, ocl = idx & 31;
            ws[jj][ocl] = wbase[(size_t)((ci * 64 + oc0 + ocl) * 3 + kk) * 192 + hc0 * 3 + jj];
        }
        __syncthreads();
        for (int c = 0; c < 32; ++c) {
#pragma unroll
            for (int t = 0; t < 3; ++t) {
                float wv8[8];
                *(float4*)&wv8[0] = *(const float4*)&ws[c * 3 + t][wv * 8];
                *(float4*)&wv8[4] = *(const float4*)&ws[c * 3 + t][wv * 8 + 4];
                float xv[4];
#pragma unroll
                for (int si = 0; si < 4; ++si) xv[si] = xs[c][lane + si * 64 + t + 3];
#pragma unroll
                for (int oi = 0; oi < 8; ++oi)
#pragma unroll
                    for (int si = 0; si < 4; ++si)
                        acc[oi][si] += wv8[oi] * xv[si];
            }
        }
    }

#pragma unroll
    for (int si = 0; si < 4; ++si) {
        int l = lane + si * 64;
        float* op = kh + ((size_t)b * LL + l) * KCL + g * 64 + oc0 + wv * 8;
        *(float4*)(op)     = make_float4(acc[0][si], acc[1][si], acc[2][si], acc[3][si]);
        *(float4*)(op + 4) = make_float4(acc[4][si], acc[5][si], acc[6][si], acc[7][si]);
    }
}

// ---------------- dilated conv 32->32 K=3, lrelu in/out ----------------
// grid (256, NB). Wave w owns 8 oc; lane owns t = t0 + lane + si*64.
__global__ void __launch_bounds__(256, 3) dilated_conv(const float* __restrict__ hsrc,
                                                       const float* __restrict__ w,
                                                       const float* __restrict__ bias,
                                                       float* __restrict__ y, int dil) {
    const int tb = blockIdx.x, b = blockIdx.y;
    const int tid = threadIdx.x, lane = tid & 63, wv = tid >> 6;
    const int t0 = tb * 256;
    __shared__ float xs[32][320];   // xs[c][j] = lrelu(h[t0 + j - 32]), cols 32-dil .. 287+dil
    __shared__ float ws[96][32];    // [c*3+k][oc]

    const float* hb = hsrc + (size_t)b * 32 * T;
    for (int idx = tid; idx < 32 * 64; idx += 256) {
        int c = idx >> 6, q = idx & 63;
        float4 v = *(const float4*)(hb + (size_t)c * T + t0 + 4 * q);
        *(float4*)&xs[c][32 + 4 * q] = make_float4(lrelu_f(v.x), lrelu_f(v.y),
                                                   lrelu_f(v.z), lrelu_f(v.w));
    }
    const int hw = 2 * dil;
    for (int idx = tid; idx < 32 * hw; idx += 256) {
        int c = idx / hw, r = idx - c * hw;
        int j = (r < dil) ? (32 - dil + r) : (288 - dil + r);
        int p = t0 + j - 32;
        xs[c][j] = (p >= 0 && p < T) ? lrelu_f(hb[(size_t)c * T + p]) : 0.f;
    }
    for (int idx = tid; idx < 3072; idx += 256) {
        int ck = idx >> 5, oc = idx & 31;
        ws[ck][oc] = w[oc * 96 + ck];
    }
    __syncthreads();

    float acc[8][4];
#pragma unroll
    for (int oi = 0; oi < 8; ++oi) {
        float bv = bias[wv * 8 + oi];
#pragma unroll
        for (int si = 0; si < 4; ++si) acc[oi][si] = bv;
    }

    for (int c = 0; c < 32; ++c) {
#pragma unroll
        for (int k = 0; k < 3; ++k) {
            const int off = 32 + (k - 1) * dil;
            float wv8[8];
            *(float4*)&wv8[0] = *(const float4*)&ws[c * 3 + k][wv * 8];
            *(float4*)&wv8[4] = *(const float4*)&ws[c * 3 + k][wv * 8 + 4];
            float xv[4];
#pragma unroll
            for (int si = 0; si < 4; ++si) xv[si] = xs[c][lane + si * 64 + off];
#pragma unroll
            for (int oi = 0; oi < 8; ++oi)
#pragma unroll
                for (int si = 0; si < 4; ++si)
                    acc[oi][si] += wv8[oi] * xv[si];
        }
    }

#pragma unroll
    for (int oi = 0; oi < 8; ++oi) {
        float* yp = y + ((size_t)b * 32 + wv * 8 + oi) * T + t0;
#pragma unroll
        for (int si = 0; si < 4; ++si)
            yp[lane + si * 64] = lrelu_f(acc[oi][si]);
    }
}

// ---------------- LVC + gated activation + residual ----------------
// grid (256, NB) = (l, b). Wave w owns gate pairs a=w*8+oi, g=32+w*8+oi; lane owns s=lane+si*64.
__global__ void __launch_bounds__(256, 2) lvc_kernel(const float* __restrict__ y,
                                                     const float* __restrict__ kh,
                                                     const float* __restrict__ bh,
                                                     float* __restrict__ h, int layer) {
    const int l = blockIdx.x, b = blockIdx.y;
    const int tid = threadIdx.x, lane = tid & 63, wv = tid >> 6;
    __shared__ float xs[32][264];   // xs[c][j] = y[b,c, l*256 + j - 4], cols 3..260
    __shared__ float ks[KCL];       // flat [c][k][oc]

    for (int idx = tid; idx < 32 * 64; idx += 256) {
        int c = idx >> 6, q = idx & 63;
        *(float4*)&xs[c][4 + 4 * q] =
            *(const float4*)(y + ((size_t)b * 32 + c) * T + l * 256 + 4 * q);
    }
    if (tid < 32) {
        int c = tid;
        xs[c][3]   = (l > 0)   ? y[((size_t)b * 32 + c) * T + l * 256 - 1]   : 0.f;
        xs[c][260] = (l < 255) ? y[((size_t)b * 32 + c) * T + l * 256 + 256] : 0.f;
    }
    {
        const float4* kp = (const float4*)(kh + ((size_t)b * LL + l) * KCL);
        float4* kd = (float4*)ks;
        for (int idx = tid; idx < KCL / 4; idx += 256) kd[idx] = kp[idx];
    }
    __syncthreads();

    float acc_a[8][4], acc_g[8][4];
#pragma unroll
    for (int oi = 0; oi < 8; ++oi) {
        float ba = bh[((size_t)b * 256 + layer * 64 + wv * 8 + oi) * LL + l];
        float bg = bh[((size_t)b * 256 + layer * 64 + 32 + wv * 8 + oi) * LL + l];
#pragma unroll
        for (int si = 0; si < 4; ++si) { acc_a[oi][si] = ba; acc_g[oi][si] = bg; }
    }

    for (int c = 0; c < 32; ++c) {
#pragma unroll
        for (int k = 0; k < 3; ++k) {
            const float* kr = ks + (c * 3 + k) * 64;
            float wa[8], wg[8];
            *(float4*)&wa[0] = *(const float4*)(kr + wv * 8);
            *(float4*)&wa[4] = *(const float4*)(kr + wv * 8 + 4);
            *(float4*)&wg[0] = *(const float4*)(kr + 32 + wv * 8);
            *(float4*)&wg[4] = *(const float4*)(kr + 32 + wv * 8 + 4);
            float xv[4];
#pragma unroll
            for (int si = 0; si < 4; ++si) xv[si] = xs[c][lane + si * 64 + k + 3];
#pragma unroll
            for (int oi = 0; oi < 8; ++oi)
#pragma unroll
                for (int si = 0; si < 4; ++si) {
                    acc_a[oi][si] += wa[oi] * xv[si];
                    acc_g[oi][si] += wg[oi] * xv[si];
                }
        }
    }

#pragma unroll
    for (int oi = 0; oi < 8; ++oi) {
        float* hp = h + ((size_t)b * 32 + wv * 8 + oi) * T + l * 256;
#pragma unroll
        for (int si = 0; si < 4; ++si) {
            float a = acc_a[oi][si], g = acc_g[oi][si];
            float sg = 1.f / (1.f + __expf(-a));
            float th = tanhf(g);
            int s = lane + si * 64;
            hp[s] = sg * th + hp[s];
        }
    }
}

extern "C" void kernel_launch(void* const* d_in, const int* in_sizes, int n_in,
                              void* d_out, int out_size, void* d_ws, size_t ws_size,
                              hipStream_t stream) {
    const float* hidden  = (const float*)d_in[0];
    const float* spec    = (const float*)d_in[1];
    const float* convt_w = (const float*)d_in[2];
    const float* convt_b = (const float*)d_in[3];
    const float* kp_in_w = (const float*)d_in[4];
    const float* kp_in_b = (const float*)d_in[5];
    const float* rb_w1   = (const float*)d_in[6];
    const float* rb_b1   = (const float*)d_in[7];
    const float* rb_w2   = (const float*)d_in[8];
    const float* rb_b2   = (const float*)d_in[9];
    const float* kern_w  = (const float*)d_in[10];
    const float* kern_b  = (const float*)d_in[11];
    const float* bias_w  = (const float*)d_in[12];
    const float* bias_b  = (const float*)d_in[13];
    const float* lvc_w   = (const float*)d_in[14];
    const float* lvc_b   = (const float*)d_in[15];

    float* h   = (float*)d_out;             // running h, (4,32,65536)
    float* wsp = (float*)d_ws;
    float* y        = wsp;                              // B*32*T     = 8,388,608 f
    float* kh_layer = y + (size_t)NB * 32 * T;          // B*256*6144 = 6,291,456 f  [b][l][m]
    float* bh       = kh_layer + (size_t)NB * LL * KCL; // B*256*256
    float* kp_h     = bh + (size_t)NB * 256 * LL;       // B*64*256
    float* kp_tmp   = kp_h + (size_t)NB * 64 * LL;      // B*64*256

    // 1) conv transpose into h
    convt_kernel<<<dim3(33, 4, NB), 256, 0, stream>>>(hidden, convt_w, convt_b, h);

    // 2) kernel predictor trunk (tiny)
    conv1d_L256<<<dim3(64, NB), 256, 100 * 5 * 4, stream>>>(spec, kp_in_w, kp_in_b, nullptr,
                                                            kp_h, 100, 5, 2, 0);
    for (int i = 0; i < 3; ++i) {
        conv1d_L256<<<dim3(64, NB), 256, 64 * 3 * 4, stream>>>(
            kp_h, rb_w1 + (size_t)i * 64 * 64 * 3, rb_b1 + i * 64, nullptr, kp_tmp, 64, 3, 1, 1);
        conv1d_L256<<<dim3(64, NB), 256, 64 * 3 * 4, stream>>>(
            kp_tmp, rb_w2 + (size_t)i * 64 * 64 * 3, rb_b2 + i * 64, kp_h, kp_h, 64, 3, 1, 2);
    }
    // bias head: all 4 layers at once, (B,256,256)
    conv1d_L256<<<dim3(256, NB), 256, 64 * 3 * 4, stream>>>(kp_h, bias_w, bias_b, nullptr,
                                                            bh, 64, 3, 1, 0);

    static const int dil[4] = {1, 3, 9, 27};
    for (int layer = 0; layer < 4; ++layer) {
        kern_head<<<dim3(192, NB), 256, 0, stream>>>(kp_h, kern_w, kern_b, kh_layer, layer);
        dilated_conv<<<dim3(T / 256, NB), 256, 0, stream>>>(
            h, lvc_w + (size_t)layer * 32 * 32 * 3, lvc_b + layer * 32, y, dil[layer]);
        lvc_kernel<<<dim3(LL, NB), 256, 0, stream>>>(y, kh_layer, bh, h, layer);
    }
}

// Round 5
// 908.529 us; speedup vs baseline: 4.0898x; 1.1207x over previous
//
#include <hip/hip_runtime.h>
#include <math.h>

#define NB 4
#define T 65536
#define TIN 8192
#define LL 256
#define KCL 6144   // per-layer kernel channels = 32*64*3

__device__ __forceinline__ float lrelu_f(float v) { return v >= 0.f ? v : 0.2f * v; }

// ---------------- ConvTranspose1d as GEMM ----------------
__global__ void __launch_bounds__(256, 3) convt_kernel(const float* __restrict__ x,
                                                       const float* __restrict__ w,
                                                       const float* __restrict__ bias,
                                                       float* __restrict__ out) {
    const int bx = blockIdx.x, mt = blockIdx.y, b = blockIdx.z;
    const int tid = threadIdx.x;
    const int lane = tid & 63, wv = tid >> 6;
    const int s0base = bx * 256;
    __shared__ float xs[32][264];   // xs[c][j] = x[b,c, s0base + j - 4], cols 3..259
    __shared__ float wm[64][64];    // [i(tap,ch)][mm = o_local*8 + k0]

    const float* xb = x + (size_t)b * 32 * TIN;
    for (int idx = tid; idx < 32 * 64; idx += 256) {
        int c = idx >> 6, q = idx & 63;
        int p = s0base + q * 4;
        float4 v = (p + 3 < TIN) ? *(const float4*)(xb + c * TIN + p)
                                 : make_float4(0.f, 0.f, 0.f, 0.f);
        *(float4*)&xs[c][4 + 4 * q] = v;
    }
    if (tid < 32) {
        int p = s0base - 1;
        xs[tid][3] = (p >= 0) ? xb[tid * TIN + p] : 0.f;
    }
    for (int idx = tid; idx < 4096; idx += 256) {
        int i = idx >> 6, mm = idx & 63;
        int oo = mt * 8 + (mm >> 3), k0 = mm & 7;
        wm[i][mm] = (i < 32) ? w[i * 512 + oo * 16 + k0]
                             : w[(i - 32) * 512 + oo * 16 + k0 + 8];
    }
    __syncthreads();

    float acc[2][8][4];   // [ol][k0][si]
#pragma unroll
    for (int ol = 0; ol < 2; ++ol) {
        float bo = bias[mt * 8 + wv * 2 + ol];
#pragma unroll
        for (int k0 = 0; k0 < 8; ++k0)
#pragma unroll
            for (int si = 0; si < 4; ++si) acc[ol][k0][si] = bo;
    }

    for (int c = 0; c < 32; ++c) {
        float xm1[4], x0[4];
#pragma unroll
        for (int si = 0; si < 4; ++si) {
            xm1[si] = xs[c][lane + si * 64 + 3];
            x0[si]  = xs[c][lane + si * 64 + 4];
        }
        float w0[16], w1[16];
#pragma unroll
        for (int q = 0; q < 4; ++q) {
            *(float4*)&w0[q * 4] = *(const float4*)&wm[c][wv * 16 + q * 4];
            *(float4*)&w1[q * 4] = *(const float4*)&wm[32 + c][wv * 16 + q * 4];
        }
#pragma unroll
        for (int ol = 0; ol < 2; ++ol)
#pragma unroll
            for (int k0 = 0; k0 < 8; ++k0)
#pragma unroll
                for (int si = 0; si < 4; ++si)
                    acc[ol][k0][si] += x0[si] * w0[ol * 8 + k0] + xm1[si] * w1[ol * 8 + k0];
    }

#pragma unroll
    for (int ol = 0; ol < 2; ++ol) {
        float* ob = out + ((size_t)b * 32 + mt * 8 + wv * 2 + ol) * T;
#pragma unroll
        for (int si = 0; si < 4; ++si) {
            int tb = (s0base + lane + si * 64) * 8 - 4;
            if (tb >= 0 && tb < T)
                *(float4*)(ob + tb) = make_float4(acc[ol][0][si], acc[ol][1][si],
                                                  acc[ol][2][si], acc[ol][3][si]);
            if (tb + 4 >= 0 && tb + 4 < T)
                *(float4*)(ob + tb + 4) = make_float4(acc[ol][4][si], acc[ol][5][si],
                                                      acc[ol][6][si], acc[ol][7][si]);
        }
    }
}

// ---------------- fused kernel-predictor trunk + bias head ----------------
// grid (8 l-chunks, NB). block 512 = 8 waves. Wave owns 8 oc; lane = j (window col).
// Window: hs[c][j], absolute l = lq*32 - 9 + j, j in [0,56).
// Chain: spec[0,50) -> h0[2,48) -> rb1:[3,47)/[4,46) -> rb2:[5,45)/[6,44)
//        -> rb3:[7,43)/[8,42) = kp_h -> write central [9,41); bias head out [9,41).
// Weights read via wave-uniform scalar loads (readfirstlane-pinned oc group).
__global__ void __launch_bounds__(512) trunk_fused(
    const float* __restrict__ spec,
    const float* __restrict__ kp_in_w, const float* __restrict__ kp_in_b,
    const float* __restrict__ rb_w1, const float* __restrict__ rb_b1,
    const float* __restrict__ rb_w2, const float* __restrict__ rb_b2,
    const float* __restrict__ bias_w, const float* __restrict__ bias_b,
    float* __restrict__ kp_h, float* __restrict__ bh) {
    const int lq = blockIdx.x, b = blockIdx.y;
    const int tid = threadIdx.x;
    const int j = tid & 63;                                        // window col
    const int wvu = __builtin_amdgcn_readfirstlane(tid >> 6);      // wave id 0..7 (uniform)
    const int oc0 = wvu * 8;
    const int l0 = lq * 32;
    const int labs = l0 - 9 + j;
    const bool lvalid = (labs >= 0 && labs < 256);

    __shared__ float hs[64][56];
    __shared__ float xsp[20][56];

    // ---- kp_in: h0 = conv(spec, K=5, pad=2), out j in [2,48) ----
    float acc[8];
#pragma unroll
    for (int oi = 0; oi < 8; ++oi) acc[oi] = kp_in_b[oc0 + oi];

    for (int cc = 0; cc < 5; ++cc) {
        __syncthreads();
        for (int idx = tid; idx < 20 * 56; idx += 512) {
            int c = idx / 56, jj = idx - c * 56;
            int l = l0 - 9 + jj;
            xsp[c][jj] = (jj < 50 && l >= 0 && l < 256)
                         ? spec[((size_t)b * 100 + cc * 20 + c) * LL + l] : 0.f;
        }
        __syncthreads();
        if (j >= 2 && j < 48) {
            for (int c = 0; c < 20; ++c) {
                float x5[5];
#pragma unroll
                for (int u = 0; u < 5; ++u) x5[u] = xsp[c][j - 2 + u];
                const float* wp = kp_in_w + (size_t)oc0 * 500 + (cc * 20 + c) * 5;
#pragma unroll
                for (int oi = 0; oi < 8; ++oi)
#pragma unroll
                    for (int k = 0; k < 5; ++k)
                        acc[oi] += x5[k] * wp[oi * 500 + k];
            }
        }
    }
    __syncthreads();
    if (j >= 2 && j < 48) {
#pragma unroll
        for (int oi = 0; oi < 8; ++oi) hs[oc0 + oi][j] = lvalid ? acc[oi] : 0.f;
    }
    __syncthreads();

    // ---- 3 residual blocks ----
    for (int i = 0; i < 3; ++i) {
        const int jlo1 = 3 + 2 * i, jhi1 = 47 - 2 * i;   // conv1 out range
        const int jlo2 = jlo1 + 1, jhi2 = jhi1 - 1;      // conv2 out range
        float r[8];
        if (j >= jlo2 && j < jhi2) {
#pragma unroll
            for (int oi = 0; oi < 8; ++oi) r[oi] = hs[oc0 + oi][j];
        }
        // conv1
        float a1[8];
#pragma unroll
        for (int oi = 0; oi < 8; ++oi) a1[oi] = rb_b1[i * 64 + oc0 + oi];
        if (j >= jlo1 && j < jhi1) {
            for (int c = 0; c < 64; ++c) {
                float x0 = hs[c][j - 1], x1 = hs[c][j], x2 = hs[c][j + 1];
                const float* wp = rb_w1 + (size_t)i * 64 * 192 + (size_t)oc0 * 192 + c * 3;
#pragma unroll
                for (int oi = 0; oi < 8; ++oi)
                    a1[oi] += x0 * wp[oi * 192] + x1 * wp[oi * 192 + 1] + x2 * wp[oi * 192 + 2];
            }
        }
        __syncthreads();
        if (j >= jlo1 && j < jhi1) {
#pragma unroll
            for (int oi = 0; oi < 8; ++oi)
                hs[oc0 + oi][j] = lvalid ? lrelu_f(a1[oi]) : 0.f;
        }
        __syncthreads();
        // conv2 + lrelu + residual
        float a2[8];
#pragma unroll
        for (int oi = 0; oi < 8; ++oi) a2[oi] = rb_b2[i * 64 + oc0 + oi];
        if (j >= jlo2 && j < jhi2) {
            for (int c = 0; c < 64; ++c) {
                float x0 = hs[c][j - 1], x1 = hs[c][j], x2 = hs[c][j + 1];
                const float* wp = rb_w2 + (size_t)i * 64 * 192 + (size_t)oc0 * 192 + c * 3;
#pragma unroll
                for (int oi = 0; oi < 8; ++oi)
                    a2[oi] += x0 * wp[oi * 192] + x1 * wp[oi * 192 + 1] + x2 * wp[oi * 192 + 2];
            }
        }
        __syncthreads();
        if (j >= jlo2 && j < jhi2) {
#pragma unroll
            for (int oi = 0; oi < 8; ++oi)
                hs[oc0 + oi][j] = lvalid ? (lrelu_f(a2[oi]) + r[oi]) : 0.f;
        }
        __syncthreads();
    }

    // ---- write kp_h (central 32 cols) ----
    for (int idx = tid; idx < 64 * 32; idx += 512) {
        int c = idx >> 5, jj = idx & 31;
        kp_h[((size_t)b * 64 + c) * LL + l0 + jj] = hs[c][9 + jj];
    }

    // ---- bias head: 256 oc, Cin=64, K=3, out j in [9,41) ----
    for (int g = 0; g < 4; ++g) {
        const int oc = g * 64 + oc0;
        float a[8];
#pragma unroll
        for (int oi = 0; oi < 8; ++oi) a[oi] = bias_b[oc + oi];
        if (j >= 9 && j < 41) {
            for (int c = 0; c < 64; ++c) {
                float x0 = hs[c][j - 1], x1 = hs[c][j], x2 = hs[c][j + 1];
                const float* wp = bias_w + (size_t)oc * 192 + c * 3;
#pragma unroll
                for (int oi = 0; oi < 8; ++oi)
                    a[oi] += x0 * wp[oi * 192] + x1 * wp[oi * 192 + 1] + x2 * wp[oi * 192 + 2];
            }
#pragma unroll
            for (int oi = 0; oi < 8; ++oi)
                bh[((size_t)b * 256 + oc + oi) * LL + labs] = a[oi];
        }
    }
}

// ---------------- kern head GEMM ----------------
__global__ void __launch_bounds__(256, 3) kern_head(const float* __restrict__ kp_h,
                                                    const float* __restrict__ kw,
                                                    const float* __restrict__ kb,
                                                    float* __restrict__ kh, int layer) {
    const int bx = blockIdx.x, b = blockIdx.y;
    const int g = bx >> 1, oc0 = (bx & 1) * 32;
    const int ci = g / 3, kk = g - ci * 3;
    const int tid = threadIdx.x, lane = tid & 63, wv = tid >> 6;
    __shared__ float xs[32][264];
    __shared__ float ws[96][32];

    float acc[8][4];
#pragma unroll
    for (int oi = 0; oi < 8; ++oi) {
        float bv = kb[layer * KCL + (ci * 64 + oc0 + wv * 8 + oi) * 3 + kk];
#pragma unroll
        for (int si = 0; si < 4; ++si) acc[oi][si] = bv;
    }

    const float* wbase = kw + (size_t)layer * KCL * 192;
    for (int half = 0; half < 2; ++half) {
        const int hc0 = half * 32;
        __syncthreads();
        for (int idx = tid; idx < 32 * 64; idx += 256) {
            int c = idx >> 6, q = idx & 63;
            *(float4*)&xs[c][4 + 4 * q] =
                *(const float4*)(kp_h + ((size_t)b * 64 + hc0 + c) * LL + 4 * q);
        }
        if (tid < 32) { xs[tid][3] = 0.f; xs[tid][260] = 0.f; }
        for (int idx = tid; idx < 3072; idx += 256) {
            int jj = idx >> 5, ocl = idx & 31;
            ws[jj][ocl] = wbase[(size_t)((ci * 64 + oc0 + ocl) * 3 + kk) * 192 + hc0 * 3 + jj];
        }
        __syncthreads();
        for (int c = 0; c < 32; ++c) {
#pragma unroll
            for (int t = 0; t < 3; ++t) {
                float wv8[8];
                *(float4*)&wv8[0] = *(const float4*)&ws[c * 3 + t][wv * 8];
                *(float4*)&wv8[4] = *(const float4*)&ws[c * 3 + t][wv * 8 + 4];
                float xv[4];
#pragma unroll
                for (int si = 0; si < 4; ++si) xv[si] = xs[c][lane + si * 64 + t + 3];
#pragma unroll
                for (int oi = 0; oi < 8; ++oi)
#pragma unroll
                    for (int si = 0; si < 4; ++si)
                        acc[oi][si] += wv8[oi] * xv[si];
            }
        }
    }

#pragma unroll
    for (int si = 0; si < 4; ++si) {
        int l = lane + si * 64;
        float* op = kh + ((size_t)b * LL + l) * KCL + g * 64 + oc0 + wv * 8;
        *(float4*)(op)     = make_float4(acc[0][si], acc[1][si], acc[2][si], acc[3][si]);
        *(float4*)(op + 4) = make_float4(acc[4][si], acc[5][si], acc[6][si], acc[7][si]);
    }
}

// ---------------- dilated conv 32->32 K=3, lrelu in/out ----------------
__global__ void __launch_bounds__(256, 3) dilated_conv(const float* __restrict__ hsrc,
                                                       const float* __restrict__ w,
                                                       const float* __restrict__ bias,
                                                       float* __restrict__ y, int dil) {
    const int tb = blockIdx.x, b = blockIdx.y;
    const int tid = threadIdx.x, lane = tid & 63, wv = tid >> 6;
    const int t0 = tb * 256;
    __shared__ float xs[32][320];
    __shared__ float ws[96][32];

    const float* hb = hsrc + (size_t)b * 32 * T;
    for (int idx = tid; idx < 32 * 64; idx += 256) {
        int c = idx >> 6, q = idx & 63;
        float4 v = *(const float4*)(hb + (size_t)c * T + t0 + 4 * q);
        *(float4*)&xs[c][32 + 4 * q] = make_float4(lrelu_f(v.x), lrelu_f(v.y),
                                                   lrelu_f(v.z), lrelu_f(v.w));
    }
    const int hw = 2 * dil;
    for (int idx = tid; idx < 32 * hw; idx += 256) {
        int c = idx / hw, r = idx - c * hw;
        int jj = (r < dil) ? (32 - dil + r) : (288 - dil + r);
        int p = t0 + jj - 32;
        xs[c][jj] = (p >= 0 && p < T) ? lrelu_f(hb[(size_t)c * T + p]) : 0.f;
    }
    for (int idx = tid; idx < 3072; idx += 256) {
        int ck = idx >> 5, oc = idx & 31;
        ws[ck][oc] = w[oc * 96 + ck];
    }
    __syncthreads();

    float acc[8][4];
#pragma unroll
    for (int oi = 0; oi < 8; ++oi) {
        float bv = bias[wv * 8 + oi];
#pragma unroll
        for (int si = 0; si < 4; ++si) acc[oi][si] = bv;
    }

    for (int c = 0; c < 32; ++c) {
#pragma unroll
        for (int k = 0; k < 3; ++k) {
            const int off = 32 + (k - 1) * dil;
            float wv8[8];
            *(float4*)&wv8[0] = *(const float4*)&ws[c * 3 + k][wv * 8];
            *(float4*)&wv8[4] = *(const float4*)&ws[c * 3 + k][wv * 8 + 4];
            float xv[4];
#pragma unroll
            for (int si = 0; si < 4; ++si) xv[si] = xs[c][lane + si * 64 + off];
#pragma unroll
            for (int oi = 0; oi < 8; ++oi)
#pragma unroll
                for (int si = 0; si < 4; ++si)
                    acc[oi][si] += wv8[oi] * xv[si];
        }
    }

#pragma unroll
    for (int oi = 0; oi < 8; ++oi) {
        float* yp = y + ((size_t)b * 32 + wv * 8 + oi) * T + t0;
#pragma unroll
        for (int si = 0; si < 4; ++si)
            yp[lane + si * 64] = lrelu_f(acc[oi][si]);
    }
}

// ---------------- LVC + gated activation + residual ----------------
__global__ void __launch_bounds__(256, 2) lvc_kernel(const float* __restrict__ y,
                                                     const float* __restrict__ kh,
                                                     const float* __restrict__ bh,
                                                     float* __restrict__ h, int layer) {
    const int l = blockIdx.x, b = blockIdx.y;
    const int tid = threadIdx.x, lane = tid & 63, wv = tid >> 6;
    __shared__ float xs[32][264];
    __shared__ float ks[KCL];

    for (int idx = tid; idx < 32 * 64; idx += 256) {
        int c = idx >> 6, q = idx & 63;
        *(float4*)&xs[c][4 + 4 * q] =
            *(const float4*)(y + ((size_t)b * 32 + c) * T + l * 256 + 4 * q);
    }
    if (tid < 32) {
        int c = tid;
        xs[c][3]   = (l > 0)   ? y[((size_t)b * 32 + c) * T + l * 256 - 1]   : 0.f;
        xs[c][260] = (l < 255) ? y[((size_t)b * 32 + c) * T + l * 256 + 256] : 0.f;
    }
    {
        const float4* kp = (const float4*)(kh + ((size_t)b * LL + l) * KCL);
        float4* kd = (float4*)ks;
        for (int idx = tid; idx < KCL / 4; idx += 256) kd[idx] = kp[idx];
    }
    __syncthreads();

    float acc_a[8][4], acc_g[8][4];
#pragma unroll
    for (int oi = 0; oi < 8; ++oi) {
        float ba = bh[((size_t)b * 256 + layer * 64 + wv * 8 + oi) * LL + l];
        float bg = bh[((size_t)b * 256 + layer * 64 + 32 + wv * 8 + oi) * LL + l];
#pragma unroll
        for (int si = 0; si < 4; ++si) { acc_a[oi][si] = ba; acc_g[oi][si] = bg; }
    }

    for (int c = 0; c < 32; ++c) {
#pragma unroll
        for (int k = 0; k < 3; ++k) {
            const float* kr = ks + (c * 3 + k) * 64;
            float wa[8], wg[8];
            *(float4*)&wa[0] = *(const float4*)(kr + wv * 8);
            *(float4*)&wa[4] = *(const float4*)(kr + wv * 8 + 4);
            *(float4*)&wg[0] = *(const float4*)(kr + 32 + wv * 8);
            *(float4*)&wg[4] = *(const float4*)(kr + 32 + wv * 8 + 4);
            float xv[4];
#pragma unroll
            for (int si = 0; si < 4; ++si) xv[si] = xs[c][lane + si * 64 + k + 3];
#pragma unroll
            for (int oi = 0; oi < 8; ++oi)
#pragma unroll
                for (int si = 0; si < 4; ++si) {
                    acc_a[oi][si] += wa[oi] * xv[si];
                    acc_g[oi][si] += wg[oi] * xv[si];
                }
        }
    }

#pragma unroll
    for (int oi = 0; oi < 8; ++oi) {
        float* hp = h + ((size_t)b * 32 + wv * 8 + oi) * T + l * 256;
#pragma unroll
        for (int si = 0; si < 4; ++si) {
            float a = acc_a[oi][si], g = acc_g[oi][si];
            float sg = 1.f / (1.f + __expf(-a));
            float th = tanhf(g);
            int s = lane + si * 64;
            hp[s] = sg * th + hp[s];
        }
    }
}

extern "C" void kernel_launch(void* const* d_in, const int* in_sizes, int n_in,
                              void* d_out, int out_size, void* d_ws, size_t ws_size,
                              hipStream_t stream) {
    const float* hidden  = (const float*)d_in[0];
    const float* spec    = (const float*)d_in[1];
    const float* convt_w = (const float*)d_in[2];
    const float* convt_b = (const float*)d_in[3];
    const float* kp_in_w = (const float*)d_in[4];
    const float* kp_in_b = (const float*)d_in[5];
    const float* rb_w1   = (const float*)d_in[6];
    const float* rb_b1   = (const float*)d_in[7];
    const float* rb_w2   = (const float*)d_in[8];
    const float* rb_b2   = (const float*)d_in[9];
    const float* kern_w  = (const float*)d_in[10];
    const float* kern_b  = (const float*)d_in[11];
    const float* bias_w  = (const float*)d_in[12];
    const float* bias_b  = (const float*)d_in[13];
    const float* lvc_w   = (const float*)d_in[14];
    const float* lvc_b   = (const float*)d_in[15];

    float* h   = (float*)d_out;             // running h, (4,32,65536)
    float* wsp = (float*)d_ws;
    float* y        = wsp;                              // B*32*T     = 8,388,608 f
    float* kh_layer = y + (size_t)NB * 32 * T;          // B*256*6144 [b][l][m]
    float* bh       = kh_layer + (size_t)NB * LL * KCL; // B*256*256
    float* kp_h     = bh + (size_t)NB * 256 * LL;       // B*64*256

    // 1) conv transpose into h
    convt_kernel<<<dim3(33, 4, NB), 256, 0, stream>>>(hidden, convt_w, convt_b, h);

    // 2) fused kernel-predictor trunk + bias head
    trunk_fused<<<dim3(8, NB), 512, 0, stream>>>(spec, kp_in_w, kp_in_b,
                                                 rb_w1, rb_b1, rb_w2, rb_b2,
                                                 bias_w, bias_b, kp_h, bh);

    static const int dil[4] = {1, 3, 9, 27};
    for (int layer = 0; layer < 4; ++layer) {
        kern_head<<<dim3(192, NB), 256, 0, stream>>>(kp_h, kern_w, kern_b, kh_layer, layer);
        dilated_conv<<<dim3(T / 256, NB), 256, 0, stream>>>(
            h, lvc_w + (size_t)layer * 32 * 32 * 3, lvc_b + layer * 32, y, dil[layer]);
        lvc_kernel<<<dim3(LL, NB), 256, 0, stream>>>(y, kh_layer, bh, h, layer);
    }
}

// Round 7
// 878.403 us; speedup vs baseline: 4.2301x; 1.0343x over previous
//
#include <hip/hip_runtime.h>
#include <math.h>

#define NB 4
#define T 65536
#define TIN 8192
#define LL 256
#define KCL 6144   // per-layer kernel channels = 32*64*3

__device__ __forceinline__ float lrelu_f(float v) { return v >= 0.f ? v : 0.2f * v; }

// ---------------- ConvTranspose1d as GEMM ----------------
__global__ void __launch_bounds__(256, 3) convt_kernel(const float* __restrict__ x,
                                                       const float* __restrict__ w,
                                                       const float* __restrict__ bias,
                                                       float* __restrict__ out) {
    const int bx = blockIdx.x, mt = blockIdx.y, b = blockIdx.z;
    const int tid = threadIdx.x;
    const int lane = tid & 63, wv = tid >> 6;
    const int s0base = bx * 256;
    __shared__ float xs[32][264];   // xs[c][j] = x[b,c, s0base + j - 4], cols 3..259
    __shared__ float wm[64][64];    // [i(tap,ch)][mm = o_local*8 + k0]

    const float* xb = x + (size_t)b * 32 * TIN;
    for (int idx = tid; idx < 32 * 64; idx += 256) {
        int c = idx >> 6, q = idx & 63;
        int p = s0base + q * 4;
        float4 v = (p + 3 < TIN) ? *(const float4*)(xb + c * TIN + p)
                                 : make_float4(0.f, 0.f, 0.f, 0.f);
        *(float4*)&xs[c][4 + 4 * q] = v;
    }
    if (tid < 32) {
        int p = s0base - 1;
        xs[tid][3] = (p >= 0) ? xb[tid * TIN + p] : 0.f;
    }
    for (int idx = tid; idx < 4096; idx += 256) {
        int i = idx >> 6, mm = idx & 63;
        int oo = mt * 8 + (mm >> 3), k0 = mm & 7;
        wm[i][mm] = (i < 32) ? w[i * 512 + oo * 16 + k0]
                             : w[(i - 32) * 512 + oo * 16 + k0 + 8];
    }
    __syncthreads();

    float acc[2][8][4];   // [ol][k0][si]
#pragma unroll
    for (int ol = 0; ol < 2; ++ol) {
        float bo = bias[mt * 8 + wv * 2 + ol];
#pragma unroll
        for (int k0 = 0; k0 < 8; ++k0)
#pragma unroll
            for (int si = 0; si < 4; ++si) acc[ol][k0][si] = bo;
    }

    for (int c = 0; c < 32; ++c) {
        float xm1[4], x0[4];
#pragma unroll
        for (int si = 0; si < 4; ++si) {
            xm1[si] = xs[c][lane + si * 64 + 3];
            x0[si]  = xs[c][lane + si * 64 + 4];
        }
        float w0[16], w1[16];
#pragma unroll
        for (int q = 0; q < 4; ++q) {
            *(float4*)&w0[q * 4] = *(const float4*)&wm[c][wv * 16 + q * 4];
            *(float4*)&w1[q * 4] = *(const float4*)&wm[32 + c][wv * 16 + q * 4];
        }
#pragma unroll
        for (int ol = 0; ol < 2; ++ol)
#pragma unroll
            for (int k0 = 0; k0 < 8; ++k0)
#pragma unroll
                for (int si = 0; si < 4; ++si)
                    acc[ol][k0][si] += x0[si] * w0[ol * 8 + k0] + xm1[si] * w1[ol * 8 + k0];
    }

#pragma unroll
    for (int ol = 0; ol < 2; ++ol) {
        float* ob = out + ((size_t)b * 32 + mt * 8 + wv * 2 + ol) * T;
#pragma unroll
        for (int si = 0; si < 4; ++si) {
            int tb = (s0base + lane + si * 64) * 8 - 4;
            if (tb >= 0 && tb < T)
                *(float4*)(ob + tb) = make_float4(acc[ol][0][si], acc[ol][1][si],
                                                  acc[ol][2][si], acc[ol][3][si]);
            if (tb + 4 >= 0 && tb + 4 < T)
                *(float4*)(ob + tb + 4) = make_float4(acc[ol][4][si], acc[ol][5][si],
                                                      acc[ol][6][si], acc[ol][7][si]);
        }
    }
}

// ---------------- fused kernel-predictor trunk + bias head (LDS-staged weights) ----------------
__global__ void __launch_bounds__(512) trunk_fused(
    const float* __restrict__ spec,
    const float* __restrict__ kp_in_w, const float* __restrict__ kp_in_b,
    const float* __restrict__ rb_w1, const float* __restrict__ rb_b1,
    const float* __restrict__ rb_w2, const float* __restrict__ rb_b2,
    const float* __restrict__ bias_w, const float* __restrict__ bias_b,
    float* __restrict__ kp_h, float* __restrict__ bh) {
    const int lq = blockIdx.x, b = blockIdx.y;
    const int tid = threadIdx.x;
    const int j = tid & 63;                                        // window col
    const int wvu = __builtin_amdgcn_readfirstlane(tid >> 6);      // wave id 0..7 (uniform)
    const int oc0 = wvu * 8;
    const int l0 = lq * 32;
    const int labs = l0 - 9 + j;
    const bool lvalid = (labs >= 0 && labs < 256);

    __shared__ float hs[64][56];     // 14.3 KB
    __shared__ float xsp[20][56];    // 4.5 KB
    __shared__ float wt[192][68];    // 52.2 KB; wt[ck][oc], padded row keeps b128 aligned

    // ---- kp_in: h0 = conv(spec, K=5, pad=2), out j in [2,48) ----
    float acc[8];
#pragma unroll
    for (int oi = 0; oi < 8; ++oi) acc[oi] = kp_in_b[oc0 + oi];

    for (int cc = 0; cc < 5; ++cc) {
        __syncthreads();
        for (int idx = tid; idx < 20 * 56; idx += 512) {
            int c = idx / 56, jj = idx - c * 56;
            int l = l0 - 9 + jj;
            xsp[c][jj] = (jj < 50 && l >= 0 && l < 256)
                         ? spec[((size_t)b * 100 + cc * 20 + c) * LL + l] : 0.f;
        }
        // stage weights: 64 oc x 100 (c*5+k); coalesced along ckl
        for (int idx = tid; idx < 6400; idx += 512) {
            int oc = idx / 100, ckl = idx - oc * 100;
            wt[ckl][oc] = kp_in_w[(size_t)oc * 500 + cc * 100 + ckl];
        }
        __syncthreads();
        if (j >= 2 && j < 48) {
            for (int c = 0; c < 20; ++c) {
                float x5[5];
#pragma unroll
                for (int u = 0; u < 5; ++u) x5[u] = xsp[c][j - 2 + u];
#pragma unroll
                for (int k = 0; k < 5; ++k) {
                    float w8[8];
                    *(float4*)&w8[0] = *(const float4*)&wt[c * 5 + k][oc0];
                    *(float4*)&w8[4] = *(const float4*)&wt[c * 5 + k][oc0 + 4];
#pragma unroll
                    for (int oi = 0; oi < 8; ++oi) acc[oi] += x5[k] * w8[oi];
                }
            }
        }
    }
    __syncthreads();
    if (j >= 2 && j < 48) {
#pragma unroll
        for (int oi = 0; oi < 8; ++oi) hs[oc0 + oi][j] = lvalid ? acc[oi] : 0.f;
    }

    // ---- 3 residual blocks ----
    for (int i = 0; i < 3; ++i) {
        const int jlo1 = 3 + 2 * i, jhi1 = 47 - 2 * i;   // conv1 out range
        const int jlo2 = jlo1 + 1, jhi2 = jhi1 - 1;      // conv2 out range

        // conv1: stage weights, then compute
        __syncthreads();
        for (int idx = tid; idx < 12288; idx += 512) {
            int oc = idx / 192, ck = idx - oc * 192;
            wt[ck][oc] = rb_w1[(size_t)i * 12288 + (size_t)oc * 192 + ck];
        }
        __syncthreads();
        float r[8];
        if (j >= jlo2 && j < jhi2) {
#pragma unroll
            for (int oi = 0; oi < 8; ++oi) r[oi] = hs[oc0 + oi][j];
        }
        float a1[8];
#pragma unroll
        for (int oi = 0; oi < 8; ++oi) a1[oi] = rb_b1[i * 64 + oc0 + oi];
        if (j >= jlo1 && j < jhi1) {
            for (int c = 0; c < 64; ++c) {
                float x0 = hs[c][j - 1], x1 = hs[c][j], x2 = hs[c][j + 1];
#pragma unroll
                for (int k = 0; k < 3; ++k) {
                    float xk = (k == 0) ? x0 : (k == 1) ? x1 : x2;
                    float w8[8];
                    *(float4*)&w8[0] = *(const float4*)&wt[c * 3 + k][oc0];
                    *(float4*)&w8[4] = *(const float4*)&wt[c * 3 + k][oc0 + 4];
#pragma unroll
                    for (int oi = 0; oi < 8; ++oi) a1[oi] += xk * w8[oi];
                }
            }
        }
        __syncthreads();
        if (j >= jlo1 && j < jhi1) {
#pragma unroll
            for (int oi = 0; oi < 8; ++oi)
                hs[oc0 + oi][j] = lvalid ? lrelu_f(a1[oi]) : 0.f;
        }

        // conv2: stage weights, then compute + lrelu + residual
        __syncthreads();
        for (int idx = tid; idx < 12288; idx += 512) {
            int oc = idx / 192, ck = idx - oc * 192;
            wt[ck][oc] = rb_w2[(size_t)i * 12288 + (size_t)oc * 192 + ck];
        }
        __syncthreads();
        float a2[8];
#pragma unroll
        for (int oi = 0; oi < 8; ++oi) a2[oi] = rb_b2[i * 64 + oc0 + oi];
        if (j >= jlo2 && j < jhi2) {
            for (int c = 0; c < 64; ++c) {
                float x0 = hs[c][j - 1], x1 = hs[c][j], x2 = hs[c][j + 1];
#pragma unroll
                for (int k = 0; k < 3; ++k) {
                    float xk = (k == 0) ? x0 : (k == 1) ? x1 : x2;
                    float w8[8];
                    *(float4*)&w8[0] = *(const float4*)&wt[c * 3 + k][oc0];
                    *(float4*)&w8[4] = *(const float4*)&wt[c * 3 + k][oc0 + 4];
#pragma unroll
                    for (int oi = 0; oi < 8; ++oi) a2[oi] += xk * w8[oi];
                }
            }
        }
        __syncthreads();
        if (j >= jlo2 && j < jhi2) {
#pragma unroll
            for (int oi = 0; oi < 8; ++oi)
                hs[oc0 + oi][j] = lvalid ? (lrelu_f(a2[oi]) + r[oi]) : 0.f;
        }
    }
    __syncthreads();

    // ---- write kp_h (central 32 cols) ----
    for (int idx = tid; idx < 64 * 32; idx += 512) {
        int c = idx >> 5, jj = idx & 31;
        kp_h[((size_t)b * 64 + c) * LL + l0 + jj] = hs[c][9 + jj];
    }

    // ---- bias head: 256 oc, Cin=64, K=3, out j in [9,41) ----
    for (int g = 0; g < 4; ++g) {
        __syncthreads();
        for (int idx = tid; idx < 12288; idx += 512) {
            int oc = idx / 192, ck = idx - oc * 192;
            wt[ck][oc] = bias_w[((size_t)g * 64 + oc) * 192 + ck];
        }
        __syncthreads();
        float a[8];
#pragma unroll
        for (int oi = 0; oi < 8; ++oi) a[oi] = bias_b[g * 64 + oc0 + oi];
        if (j >= 9 && j < 41) {
            for (int c = 0; c < 64; ++c) {
                float x0 = hs[c][j - 1], x1 = hs[c][j], x2 = hs[c][j + 1];
#pragma unroll
                for (int k = 0; k < 3; ++k) {
                    float xk = (k == 0) ? x0 : (k == 1) ? x1 : x2;
                    float w8[8];
                    *(float4*)&w8[0] = *(const float4*)&wt[c * 3 + k][oc0];
                    *(float4*)&w8[4] = *(const float4*)&wt[c * 3 + k][oc0 + 4];
#pragma unroll
                    for (int oi = 0; oi < 8; ++oi) a[oi] += xk * w8[oi];
                }
            }
#pragma unroll
            for (int oi = 0; oi < 8; ++oi)
                bh[((size_t)b * 256 + g * 64 + oc0 + oi) * LL + labs] = a[oi];
        }
    }
}

// ---------------- kern head GEMM ----------------
__global__ void __launch_bounds__(256, 3) kern_head(const float* __restrict__ kp_h,
                                                    const float* __restrict__ kw,
                                                    const float* __restrict__ kb,
                                                    float* __restrict__ kh, int layer) {
    const int bx = blockIdx.x, b = blockIdx.y;
    const int g = bx >> 1, oc0 = (bx & 1) * 32;
    const int ci = g / 3, kk = g - ci * 3;
    const int tid = threadIdx.x, lane = tid & 63, wv = tid >> 6;
    __shared__ float xs[32][264];
    __shared__ float ws[96][36];

    float acc[8][4];
#pragma unroll
    for (int oi = 0; oi < 8; ++oi) {
        float bv = kb[layer * KCL + (ci * 64 + oc0 + wv * 8 + oi) * 3 + kk];
#pragma unroll
        for (int si = 0; si < 4; ++si) acc[oi][si] = bv;
    }

    const float* wbase = kw + (size_t)layer * KCL * 192;
    for (int half = 0; half < 2; ++half) {
        const int hc0 = half * 32;
        __syncthreads();
        for (int idx = tid; idx < 32 * 64; idx += 256) {
            int c = idx >> 6, q = idx & 63;
            *(float4*)&xs[c][4 + 4 * q] =
                *(const float4*)(kp_h + ((size_t)b * 64 + hc0 + c) * LL + 4 * q);
        }
        if (tid < 32) { xs[tid][3] = 0.f; xs[tid][260] = 0.f; }
        for (int idx = tid; idx < 3072; idx += 256) {
            int ocl = idx / 96, jj = idx - ocl * 96;   // coalesced along jj
            ws[jj][ocl] = wbase[(size_t)((ci * 64 + oc0 + ocl) * 3 + kk) * 192 + hc0 * 3 + jj];
        }
        __syncthreads();
        for (int c = 0; c < 32; ++c) {
#pragma unroll
            for (int t = 0; t < 3; ++t) {
                float wv8[8];
                *(float4*)&wv8[0] = *(const float4*)&ws[c * 3 + t][wv * 8];
                *(float4*)&wv8[4] = *(const float4*)&ws[c * 3 + t][wv * 8 + 4];
                float xv[4];
#pragma unroll
                for (int si = 0; si < 4; ++si) xv[si] = xs[c][lane + si * 64 + t + 3];
#pragma unroll
                for (int oi = 0; oi < 8; ++oi)
#pragma unroll
                    for (int si = 0; si < 4; ++si)
                        acc[oi][si] += wv8[oi] * xv[si];
            }
        }
    }

#pragma unroll
    for (int si = 0; si < 4; ++si) {
        int l = lane + si * 64;
        float* op = kh + ((size_t)b * LL + l) * KCL + g * 64 + oc0 + wv * 8;
        *(float4*)(op)     = make_float4(acc[0][si], acc[1][si], acc[2][si], acc[3][si]);
        *(float4*)(op + 4) = make_float4(acc[4][si], acc[5][si], acc[6][si], acc[7][si]);
    }
}

// ---------------- dilated conv 32->32 K=3, lrelu in/out ----------------
// xs width must cover halo writes up to 288+dil-1 = 314 (dil=27) and reads to 314 -> 320.
__global__ void __launch_bounds__(256) dilated_conv(const float* __restrict__ hsrc,
                                                    const float* __restrict__ w,
                                                    const float* __restrict__ bias,
                                                    float* __restrict__ y, int dil) {
    const int tb = blockIdx.x, b = blockIdx.y;
    const int tid = threadIdx.x, lane = tid & 63, wv = tid >> 6;
    const int t0 = tb * 256;
    __shared__ float xs[32][320];
    __shared__ float ws[96][36];

    const float* hb = hsrc + (size_t)b * 32 * T;
    for (int idx = tid; idx < 32 * 64; idx += 256) {
        int c = idx >> 6, q = idx & 63;
        float4 v = *(const float4*)(hb + (size_t)c * T + t0 + 4 * q);
        *(float4*)&xs[c][32 + 4 * q] = make_float4(lrelu_f(v.x), lrelu_f(v.y),
                                                   lrelu_f(v.z), lrelu_f(v.w));
    }
    const int hw = 2 * dil;
    for (int idx = tid; idx < 32 * hw; idx += 256) {
        int c = idx / hw, r = idx - c * hw;
        int jj = (r < dil) ? (32 - dil + r) : (288 - dil + r);
        int p = t0 + jj - 32;
        xs[c][jj] = (p >= 0 && p < T) ? lrelu_f(hb[(size_t)c * T + p]) : 0.f;
    }
    for (int idx = tid; idx < 3072; idx += 256) {
        int oc = idx / 96, ck = idx - oc * 96;   // coalesced along ck
        ws[ck][oc] = w[oc * 96 + ck];
    }
    __syncthreads();

    float acc[8][4];
#pragma unroll
    for (int oi = 0; oi < 8; ++oi) {
        float bv = bias[wv * 8 + oi];
#pragma unroll
        for (int si = 0; si < 4; ++si) acc[oi][si] = bv;
    }

    for (int c = 0; c < 32; ++c) {
#pragma unroll
        for (int k = 0; k < 3; ++k) {
            const int off = 32 + (k - 1) * dil;
            float wv8[8];
            *(float4*)&wv8[0] = *(const float4*)&ws[c * 3 + k][wv * 8];
            *(float4*)&wv8[4] = *(const float4*)&ws[c * 3 + k][wv * 8 + 4];
            float xv[4];
#pragma unroll
            for (int si = 0; si < 4; ++si) xv[si] = xs[c][lane + si * 64 + off];
#pragma unroll
            for (int oi = 0; oi < 8; ++oi)
#pragma unroll
                for (int si = 0; si < 4; ++si)
                    acc[oi][si] += wv8[oi] * xv[si];
        }
    }

#pragma unroll
    for (int oi = 0; oi < 8; ++oi) {
        float* yp = y + ((size_t)b * 32 + wv * 8 + oi) * T + t0;
#pragma unroll
        for (int si = 0; si < 4; ++si)
            yp[lane + si * 64] = lrelu_f(acc[oi][si]);
    }
}

// ---------------- LVC + gated activation + residual ----------------
__global__ void __launch_bounds__(256, 2) lvc_kernel(const float* __restrict__ y,
                                                     const float* __restrict__ kh,
                                                     const float* __restrict__ bh,
                                                     float* __restrict__ h, int layer) {
    const int l = blockIdx.x, b = blockIdx.y;
    const int tid = threadIdx.x, lane = tid & 63, wv = tid >> 6;
    __shared__ float xs[32][264];
    __shared__ float ks[KCL];

    for (int idx = tid; idx < 32 * 64; idx += 256) {
        int c = idx >> 6, q = idx & 63;
        *(float4*)&xs[c][4 + 4 * q] =
            *(const float4*)(y + ((size_t)b * 32 + c) * T + l * 256 + 4 * q);
    }
    if (tid < 32) {
        int c = tid;
        xs[c][3]   = (l > 0)   ? y[((size_t)b * 32 + c) * T + l * 256 - 1]   : 0.f;
        xs[c][260] = (l < 255) ? y[((size_t)b * 32 + c) * T + l * 256 + 256] : 0.f;
    }
    {
        const float4* kp = (const float4*)(kh + ((size_t)b * LL + l) * KCL);
        float4* kd = (float4*)ks;
        for (int idx = tid; idx < KCL / 4; idx += 256) kd[idx] = kp[idx];
    }
    __syncthreads();

    float acc_a[8][4], acc_g[8][4];
#pragma unroll
    for (int oi = 0; oi < 8; ++oi) {
        float ba = bh[((size_t)b * 256 + layer * 64 + wv * 8 + oi) * LL + l];
        float bg = bh[((size_t)b * 256 + layer * 64 + 32 + wv * 8 + oi) * LL + l];
#pragma unroll
        for (int si = 0; si < 4; ++si) { acc_a[oi][si] = ba; acc_g[oi][si] = bg; }
    }

    for (int c = 0; c < 32; ++c) {
#pragma unroll
        for (int k = 0; k < 3; ++k) {
            const float* kr = ks + (c * 3 + k) * 64;
            float wa[8], wg[8];
            *(float4*)&wa[0] = *(const float4*)(kr + wv * 8);
            *(float4*)&wa[4] = *(const float4*)(kr + wv * 8 + 4);
            *(float4*)&wg[0] = *(const float4*)(kr + 32 + wv * 8);
            *(float4*)&wg[4] = *(const float4*)(kr + 32 + wv * 8 + 4);
            float xv[4];
#pragma unroll
            for (int si = 0; si < 4; ++si) xv[si] = xs[c][lane + si * 64 + k + 3];
#pragma unroll
            for (int oi = 0; oi < 8; ++oi)
#pragma unroll
                for (int si = 0; si < 4; ++si) {
                    acc_a[oi][si] += wa[oi] * xv[si];
                    acc_g[oi][si] += wg[oi] * xv[si];
                }
        }
    }

#pragma unroll
    for (int oi = 0; oi < 8; ++oi) {
        float* hp = h + ((size_t)b * 32 + wv * 8 + oi) * T + l * 256;
#pragma unroll
        for (int si = 0; si < 4; ++si) {
            float a = acc_a[oi][si], g = acc_g[oi][si];
            float sg = 1.f / (1.f + __expf(-a));
            float th = tanhf(g);
            int s = lane + si * 64;
            hp[s] = sg * th + hp[s];
        }
    }
}

extern "C" void kernel_launch(void* const* d_in, const int* in_sizes, int n_in,
                              void* d_out, int out_size, void* d_ws, size_t ws_size,
                              hipStream_t stream) {
    const float* hidden  = (const float*)d_in[0];
    const float* spec    = (const float*)d_in[1];
    const float* convt_w = (const float*)d_in[2];
    const float* convt_b = (const float*)d_in[3];
    const float* kp_in_w = (const float*)d_in[4];
    const float* kp_in_b = (const float*)d_in[5];
    const float* rb_w1   = (const float*)d_in[6];
    const float* rb_b1   = (const float*)d_in[7];
    const float* rb_w2   = (const float*)d_in[8];
    const float* rb_b2   = (const float*)d_in[9];
    const float* kern_w  = (const float*)d_in[10];
    const float* kern_b  = (const float*)d_in[11];
    const float* bias_w  = (const float*)d_in[12];
    const float* bias_b  = (const float*)d_in[13];
    const float* lvc_w   = (const float*)d_in[14];
    const float* lvc_b   = (const float*)d_in[15];

    float* h   = (float*)d_out;             // running h, (4,32,65536)
    float* wsp = (float*)d_ws;
    float* y        = wsp;                              // B*32*T     = 8,388,608 f
    float* kh_layer = y + (size_t)NB * 32 * T;          // B*256*6144 [b][l][m]
    float* bh       = kh_layer + (size_t)NB * LL * KCL; // B*256*256
    float* kp_h     = bh + (size_t)NB * 256 * LL;       // B*64*256

    // 1) conv transpose into h
    convt_kernel<<<dim3(33, 4, NB), 256, 0, stream>>>(hidden, convt_w, convt_b, h);

    // 2) fused kernel-predictor trunk + bias head
    trunk_fused<<<dim3(8, NB), 512, 0, stream>>>(spec, kp_in_w, kp_in_b,
                                                 rb_w1, rb_b1, rb_w2, rb_b2,
                                                 bias_w, bias_b, kp_h, bh);

    static const int dil[4] = {1, 3, 9, 27};
    for (int layer = 0; layer < 4; ++layer) {
        kern_head<<<dim3(192, NB), 256, 0, stream>>>(kp_h, kern_w, kern_b, kh_layer, layer);
        dilated_conv<<<dim3(T / 256, NB), 256, 0, stream>>>(
            h, lvc_w + (size_t)layer * 32 * 32 * 3, lvc_b + layer * 32, y, dil[layer]);
        lvc_kernel<<<dim3(LL, NB), 256, 0, stream>>>(y, kh_layer, bh, h, layer);
    }
}

// Round 8
// 785.348 us; speedup vs baseline: 4.7313x; 1.1185x over previous
//
#include <hip/hip_runtime.h>
#include <math.h>

#define NB 4
#define T 65536
#define TIN 8192
#define LL 256
#define KCL 6144   // per-layer kernel channels = 32*64*3

__device__ __forceinline__ float lrelu_f(float v) { return v >= 0.f ? v : 0.2f * v; }

// ---------------- ConvTranspose1d as GEMM ----------------
__global__ void __launch_bounds__(256, 3) convt_kernel(const float* __restrict__ x,
                                                       const float* __restrict__ w,
                                                       const float* __restrict__ bias,
                                                       float* __restrict__ out) {
    const int bx = blockIdx.x, mt = blockIdx.y, b = blockIdx.z;
    const int tid = threadIdx.x;
    const int lane = tid & 63, wv = tid >> 6;
    const int s0base = bx * 256;
    __shared__ float xs[32][264];   // xs[c][j] = x[b,c, s0base + j - 4], cols 3..259
    __shared__ float wm[64][64];    // [i(tap,ch)][mm = o_local*8 + k0]

    const float* xb = x + (size_t)b * 32 * TIN;
    for (int idx = tid; idx < 32 * 64; idx += 256) {
        int c = idx >> 6, q = idx & 63;
        int p = s0base + q * 4;
        float4 v = (p + 3 < TIN) ? *(const float4*)(xb + c * TIN + p)
                                 : make_float4(0.f, 0.f, 0.f, 0.f);
        *(float4*)&xs[c][4 + 4 * q] = v;
    }
    if (tid < 32) {
        int p = s0base - 1;
        xs[tid][3] = (p >= 0) ? xb[tid * TIN + p] : 0.f;
    }
    for (int idx = tid; idx < 4096; idx += 256) {
        int i = idx >> 6, mm = idx & 63;
        int oo = mt * 8 + (mm >> 3), k0 = mm & 7;
        wm[i][mm] = (i < 32) ? w[i * 512 + oo * 16 + k0]
                             : w[(i - 32) * 512 + oo * 16 + k0 + 8];
    }
    __syncthreads();

    float acc[2][8][4];   // [ol][k0][si]
#pragma unroll
    for (int ol = 0; ol < 2; ++ol) {
        float bo = bias[mt * 8 + wv * 2 + ol];
#pragma unroll
        for (int k0 = 0; k0 < 8; ++k0)
#pragma unroll
            for (int si = 0; si < 4; ++si) acc[ol][k0][si] = bo;
    }

    for (int c = 0; c < 32; ++c) {
        float xm1[4], x0[4];
#pragma unroll
        for (int si = 0; si < 4; ++si) {
            xm1[si] = xs[c][lane + si * 64 + 3];
            x0[si]  = xs[c][lane + si * 64 + 4];
        }
        float w0[16], w1[16];
#pragma unroll
        for (int q = 0; q < 4; ++q) {
            *(float4*)&w0[q * 4] = *(const float4*)&wm[c][wv * 16 + q * 4];
            *(float4*)&w1[q * 4] = *(const float4*)&wm[32 + c][wv * 16 + q * 4];
        }
#pragma unroll
        for (int ol = 0; ol < 2; ++ol)
#pragma unroll
            for (int k0 = 0; k0 < 8; ++k0)
#pragma unroll
                for (int si = 0; si < 4; ++si)
                    acc[ol][k0][si] += x0[si] * w0[ol * 8 + k0] + xm1[si] * w1[ol * 8 + k0];
    }

#pragma unroll
    for (int ol = 0; ol < 2; ++ol) {
        float* ob = out + ((size_t)b * 32 + mt * 8 + wv * 2 + ol) * T;
#pragma unroll
        for (int si = 0; si < 4; ++si) {
            int tb = (s0base + lane + si * 64) * 8 - 4;
            if (tb >= 0 && tb < T)
                *(float4*)(ob + tb) = make_float4(acc[ol][0][si], acc[ol][1][si],
                                                  acc[ol][2][si], acc[ol][3][si]);
            if (tb + 4 >= 0 && tb + 4 < T)
                *(float4*)(ob + tb + 4) = make_float4(acc[ol][4][si], acc[ol][5][si],
                                                      acc[ol][6][si], acc[ol][7][si]);
        }
    }
}

// ---------------- fused trunk + bias head, v3: software-pipelined weight pages ----------------
// grid (8, NB). block 512 = 8 waves. Wave owns 8 oc; lane = j (window col, 56 used).
// Page pipeline: prefetch next page's weights into regs BEFORE computing current page.
__global__ void __launch_bounds__(512) trunk_fused(
    const float* __restrict__ spec,
    const float* __restrict__ kp_in_w, const float* __restrict__ kp_in_b,
    const float* __restrict__ rb_w1, const float* __restrict__ rb_b1,
    const float* __restrict__ rb_w2, const float* __restrict__ rb_b2,
    const float* __restrict__ bias_w, const float* __restrict__ bias_b,
    float* __restrict__ kp_h, float* __restrict__ bh) {
    const int lq = blockIdx.x, b = blockIdx.y;
    const int tid = threadIdx.x;
    const int j = tid & 63;
    const int wvu = tid >> 6;
    const int oc0 = wvu * 8;
    const int l0 = lq * 32;
    const int labs = l0 - 9 + j;
    const bool lvalid = (labs >= 0 && labs < 256);

    __shared__ float hs[64][56];
    __shared__ float xsp[20][56];
    __shared__ float wt[192][68];

    float pw[24];
    float px[3];

    auto pf_kpin = [&](int cc) {
#pragma unroll
        for (int t = 0; t < 13; ++t) {
            int idx = t * 512 + tid;
            pw[t] = 0.f;
            if (idx < 6400) pw[t] = kp_in_w[(size_t)(idx / 100) * 500 + cc * 100 + (idx % 100)];
        }
    };
    auto wr_kpin = [&]() {
#pragma unroll
        for (int t = 0; t < 13; ++t) {
            int idx = t * 512 + tid;
            if (idx < 6400) wt[idx % 100][idx / 100] = pw[t];
        }
    };
    auto pf_xsp = [&](int cc) {
#pragma unroll
        for (int t = 0; t < 3; ++t) {
            int idx = t * 512 + tid;
            px[t] = 0.f;
            if (idx < 1120) {
                int c = idx / 56, jj = idx - c * 56;
                int l = l0 - 9 + jj;
                if (l >= 0 && l < 256)
                    px[t] = spec[((size_t)b * 100 + cc * 20 + c) * LL + l];
            }
        }
    };
    auto wr_xsp = [&]() {
#pragma unroll
        for (int t = 0; t < 3; ++t) {
            int idx = t * 512 + tid;
            if (idx < 1120) xsp[idx / 56][idx % 56] = px[t];
        }
    };
    auto pf_w192 = [&](const float* src) {   // 12288-float page [64oc][192]
#pragma unroll
        for (int t = 0; t < 24; ++t) pw[t] = src[t * 512 + tid];
    };
    auto wr_w192 = [&]() {
#pragma unroll
        for (int t = 0; t < 24; ++t) {
            int idx = t * 512 + tid;
            wt[idx % 192][idx / 192] = pw[t];
        }
    };
    // conv 64->8oc K=3 from hs + wt
    auto conv64 = [&](int jlo, int jhi, const float* bptr, float* a) {
#pragma unroll
        for (int oi = 0; oi < 8; ++oi) a[oi] = bptr[oc0 + oi];
        if (j >= jlo && j < jhi) {
            for (int c = 0; c < 64; ++c) {
                float x0 = hs[c][j - 1], x1 = hs[c][j], x2 = hs[c][j + 1];
#pragma unroll
                for (int k = 0; k < 3; ++k) {
                    float xk = (k == 0) ? x0 : (k == 1) ? x1 : x2;
                    float w8[8];
                    *(float4*)&w8[0] = *(const float4*)&wt[c * 3 + k][oc0];
                    *(float4*)&w8[4] = *(const float4*)&wt[c * 3 + k][oc0 + 4];
#pragma unroll
                    for (int oi = 0; oi < 8; ++oi) a[oi] += xk * w8[oi];
                }
            }
        }
    };

    // ---- kp_in: 5 cc pages ----
    pf_kpin(0); pf_xsp(0);
    wr_kpin(); wr_xsp();
    __syncthreads();

    float acc[8];
#pragma unroll
    for (int oi = 0; oi < 8; ++oi) acc[oi] = kp_in_b[oc0 + oi];

    for (int cc = 0; cc < 5; ++cc) {
        if (cc < 4) { pf_kpin(cc + 1); pf_xsp(cc + 1); }
        else        { pf_w192(rb_w1); }
        if (j >= 2 && j < 48) {
            for (int c = 0; c < 20; ++c) {
                float x5[5];
#pragma unroll
                for (int u = 0; u < 5; ++u) x5[u] = xsp[c][j - 2 + u];
#pragma unroll
                for (int k = 0; k < 5; ++k) {
                    float w8[8];
                    *(float4*)&w8[0] = *(const float4*)&wt[c * 5 + k][oc0];
                    *(float4*)&w8[4] = *(const float4*)&wt[c * 5 + k][oc0 + 4];
#pragma unroll
                    for (int oi = 0; oi < 8; ++oi) acc[oi] += x5[k] * w8[oi];
                }
            }
        }
        if (cc == 4 && j >= 2 && j < 48) {
#pragma unroll
            for (int oi = 0; oi < 8; ++oi) hs[oc0 + oi][j] = lvalid ? acc[oi] : 0.f;
        }
        __syncthreads();
        if (cc < 4) { wr_kpin(); wr_xsp(); }
        else        { wr_w192(); }
        __syncthreads();
    }

    // ---- 3 residual blocks (wt holds rb_w1[0] now) ----
    for (int i = 0; i < 3; ++i) {
        const int jlo1 = 3 + 2 * i, jhi1 = 47 - 2 * i;
        const int jlo2 = jlo1 + 1, jhi2 = jhi1 - 1;
        float r[8];
        if (j >= jlo2 && j < jhi2) {
#pragma unroll
            for (int oi = 0; oi < 8; ++oi) r[oi] = hs[oc0 + oi][j];
        }
        // conv1
        pf_w192(rb_w2 + (size_t)i * 12288);
        float a1[8];
        conv64(jlo1, jhi1, rb_b1 + i * 64, a1);
        __syncthreads();
        if (j >= jlo1 && j < jhi1) {
#pragma unroll
            for (int oi = 0; oi < 8; ++oi) hs[oc0 + oi][j] = lvalid ? lrelu_f(a1[oi]) : 0.f;
        }
        wr_w192();
        __syncthreads();
        // conv2
        pf_w192(i < 2 ? rb_w1 + (size_t)(i + 1) * 12288 : bias_w);
        float a2[8];
        conv64(jlo2, jhi2, rb_b2 + i * 64, a2);
        __syncthreads();
        if (j >= jlo2 && j < jhi2) {
#pragma unroll
            for (int oi = 0; oi < 8; ++oi) hs[oc0 + oi][j] = lvalid ? (lrelu_f(a2[oi]) + r[oi]) : 0.f;
        }
        wr_w192();
        __syncthreads();
    }

    // ---- write kp_h (central 32 cols); hs is final ----
    for (int idx = tid; idx < 64 * 32; idx += 512) {
        int c = idx >> 5, jj = idx & 31;
        kp_h[((size_t)b * 64 + c) * LL + l0 + jj] = hs[c][9 + jj];
    }

    // ---- bias head: 4 pages of 64 oc (wt holds bias_w g0) ----
    for (int g = 0; g < 4; ++g) {
        if (g < 3) pf_w192(bias_w + (size_t)(g + 1) * 12288);
        float a[8];
        conv64(9, 41, bias_b + g * 64, a);
        if (j >= 9 && j < 41) {
#pragma unroll
            for (int oi = 0; oi < 8; ++oi)
                bh[((size_t)b * 256 + g * 64 + oc0 + oi) * LL + labs] = a[oi];
        }
        if (g < 3) {
            __syncthreads();
            wr_w192();
            __syncthreads();
        }
    }
}

// ---------------- kern head GEMM ----------------
__global__ void __launch_bounds__(256, 3) kern_head(const float* __restrict__ kp_h,
                                                    const float* __restrict__ kw,
                                                    const float* __restrict__ kb,
                                                    float* __restrict__ kh, int layer) {
    const int bx = blockIdx.x, b = blockIdx.y;
    const int g = bx >> 1, oc0 = (bx & 1) * 32;
    const int ci = g / 3, kk = g - ci * 3;
    const int tid = threadIdx.x, lane = tid & 63, wv = tid >> 6;
    __shared__ float xs[32][264];
    __shared__ float ws[96][36];

    float acc[8][4];
#pragma unroll
    for (int oi = 0; oi < 8; ++oi) {
        float bv = kb[layer * KCL + (ci * 64 + oc0 + wv * 8 + oi) * 3 + kk];
#pragma unroll
        for (int si = 0; si < 4; ++si) acc[oi][si] = bv;
    }

    const float* wbase = kw + (size_t)layer * KCL * 192;
    for (int half = 0; half < 2; ++half) {
        const int hc0 = half * 32;
        __syncthreads();
        for (int idx = tid; idx < 32 * 64; idx += 256) {
            int c = idx >> 6, q = idx & 63;
            *(float4*)&xs[c][4 + 4 * q] =
                *(const float4*)(kp_h + ((size_t)b * 64 + hc0 + c) * LL + 4 * q);
        }
        if (tid < 32) { xs[tid][3] = 0.f; xs[tid][260] = 0.f; }
        for (int idx = tid; idx < 3072; idx += 256) {
            int ocl = idx / 96, jj = idx - ocl * 96;
            ws[jj][ocl] = wbase[(size_t)((ci * 64 + oc0 + ocl) * 3 + kk) * 192 + hc0 * 3 + jj];
        }
        __syncthreads();
        for (int c = 0; c < 32; ++c) {
#pragma unroll
            for (int t = 0; t < 3; ++t) {
                float wv8[8];
                *(float4*)&wv8[0] = *(const float4*)&ws[c * 3 + t][wv * 8];
                *(float4*)&wv8[4] = *(const float4*)&ws[c * 3 + t][wv * 8 + 4];
                float xv[4];
#pragma unroll
                for (int si = 0; si < 4; ++si) xv[si] = xs[c][lane + si * 64 + t + 3];
#pragma unroll
                for (int oi = 0; oi < 8; ++oi)
#pragma unroll
                    for (int si = 0; si < 4; ++si)
                        acc[oi][si] += wv8[oi] * xv[si];
            }
        }
    }

#pragma unroll
    for (int si = 0; si < 4; ++si) {
        int l = lane + si * 64;
        float* op = kh + ((size_t)b * LL + l) * KCL + g * 64 + oc0 + wv * 8;
        *(float4*)(op)     = make_float4(acc[0][si], acc[1][si], acc[2][si], acc[3][si]);
        *(float4*)(op + 4) = make_float4(acc[4][si], acc[5][si], acc[6][si], acc[7][si]);
    }
}

// ---------------- fused dilated conv + LVC + gate + residual ----------------
// grid (256 l, NB b), block 512 = 8 waves. h ping-pong: reads hin, writes hout.
// xh[c][j] = lrelu(hin[t0 + j - 32]) for j in [0,316); after barrier, central
// region [31,289) is overwritten with y[t], t = t0 - 1 + (j - 31).
__global__ void __launch_bounds__(512, 4) layer_fused(
    const float* __restrict__ kh, const float* __restrict__ bh,
    const float* __restrict__ w, const float* __restrict__ bias,
    const float* __restrict__ hin, float* __restrict__ hout,
    int layer, int dil) {
    const int l = blockIdx.x, b = blockIdx.y;
    const int tid = threadIdx.x, lane = tid & 63, wv = tid >> 6;
    const int t0 = l * 256;
    __shared__ float xh[32][316];   // 40.4 KB
    __shared__ float ks[KCL];       // 24.6 KB
    __shared__ float ws[96][36];    // 13.8 KB

    const float* hb = hin + (size_t)b * 32 * T;
    for (int idx = tid; idx < 32 * 316; idx += 512) {
        int c = idx / 316, jj = idx - c * 316;
        int t = t0 + jj - 32;
        xh[c][jj] = (t >= 0 && t < T) ? lrelu_f(hb[(size_t)c * T + t]) : 0.f;
    }
    {
        const float4* kp = (const float4*)(kh + ((size_t)b * LL + l) * KCL);
        float4* kd = (float4*)ks;
        for (int idx = tid; idx < KCL / 4; idx += 512) kd[idx] = kp[idx];
    }
    for (int idx = tid; idx < 3072; idx += 512) {
        int oc = idx / 96, ck = idx - oc * 96;
        ws[ck][oc] = w[oc * 96 + ck];
    }
    __syncthreads();

    // Phase B: dilated conv -> y regs. wave wv owns oc4 = wv*4; col = lane + si*64, col<258.
    const int oc4 = wv * 4;
    float yv[5][4];
    {
        float a[5][4];
#pragma unroll
        for (int oi = 0; oi < 4; ++oi) {
            float bv = bias[oc4 + oi];
#pragma unroll
            for (int si = 0; si < 5; ++si) a[si][oi] = bv;
        }
        for (int c = 0; c < 32; ++c) {
#pragma unroll
            for (int k = 0; k < 3; ++k) {
                float4 wq = *(const float4*)&ws[c * 3 + k][oc4];
                float xv[5];
#pragma unroll
                for (int si = 0; si < 5; ++si) {
                    int col = lane + si * 64;
                    int colc = (col < 258) ? col : 257;
                    xv[si] = xh[c][colc + 31 + (k - 1) * dil];
                }
#pragma unroll
                for (int si = 0; si < 5; ++si) {
                    a[si][0] += xv[si] * wq.x;
                    a[si][1] += xv[si] * wq.y;
                    a[si][2] += xv[si] * wq.z;
                    a[si][3] += xv[si] * wq.w;
                }
            }
        }
#pragma unroll
        for (int si = 0; si < 5; ++si) {
            int t = t0 - 1 + lane + si * 64;
            bool tval = (t >= 0 && t < T);
#pragma unroll
            for (int oi = 0; oi < 4; ++oi)
                yv[si][oi] = tval ? lrelu_f(a[si][oi]) : 0.f;
        }
    }
    __syncthreads();   // all xh reads done

    // Phase C: write y into xh central region
#pragma unroll
    for (int si = 0; si < 5; ++si) {
        int col = lane + si * 64;
        if (col < 258) {
#pragma unroll
            for (int oi = 0; oi < 4; ++oi) xh[oc4 + oi][col + 31] = yv[si][oi];
        }
    }
    __syncthreads();

    // Phase D: LVC. wave wv: aw = wv&3 -> oc8; sh = wv>>2 -> s half.
    const int oc8 = (wv & 3) * 8;
    const int sh  = wv >> 2;
    float acc_a[8][2], acc_g[8][2];
#pragma unroll
    for (int oi = 0; oi < 8; ++oi) {
        float ba = bh[((size_t)b * 256 + layer * 64 + oc8 + oi) * LL + l];
        float bg = bh[((size_t)b * 256 + layer * 64 + 32 + oc8 + oi) * LL + l];
#pragma unroll
        for (int si = 0; si < 2; ++si) { acc_a[oi][si] = ba; acc_g[oi][si] = bg; }
    }

    for (int c = 0; c < 32; ++c) {
#pragma unroll
        for (int k = 0; k < 3; ++k) {
            const float* kr = ks + (c * 3 + k) * 64;
            float wa[8], wg[8];
            *(float4*)&wa[0] = *(const float4*)(kr + oc8);
            *(float4*)&wa[4] = *(const float4*)(kr + oc8 + 4);
            *(float4*)&wg[0] = *(const float4*)(kr + 32 + oc8);
            *(float4*)&wg[4] = *(const float4*)(kr + 32 + oc8 + 4);
            float xv2[2];
#pragma unroll
            for (int si = 0; si < 2; ++si) {
                int s = lane + (sh * 2 + si) * 64;
                xv2[si] = xh[c][s + k + 31];
            }
#pragma unroll
            for (int oi = 0; oi < 8; ++oi)
#pragma unroll
                for (int si = 0; si < 2; ++si) {
                    acc_a[oi][si] += wa[oi] * xv2[si];
                    acc_g[oi][si] += wg[oi] * xv2[si];
                }
        }
    }

    // Phase E: gate + residual (reads hin, writes hout)
#pragma unroll
    for (int oi = 0; oi < 8; ++oi) {
        const float* hip = hin + ((size_t)b * 32 + oc8 + oi) * T + t0;
        float* hop = hout + ((size_t)b * 32 + oc8 + oi) * T + t0;
#pragma unroll
        for (int si = 0; si < 2; ++si) {
            int s = lane + (sh * 2 + si) * 64;
            float a = acc_a[oi][si], g = acc_g[oi][si];
            float sg = 1.f / (1.f + __expf(-a));
            float th = tanhf(g);
            hop[s] = sg * th + hip[s];
        }
    }
}

extern "C" void kernel_launch(void* const* d_in, const int* in_sizes, int n_in,
                              void* d_out, int out_size, void* d_ws, size_t ws_size,
                              hipStream_t stream) {
    const float* hidden  = (const float*)d_in[0];
    const float* spec    = (const float*)d_in[1];
    const float* convt_w = (const float*)d_in[2];
    const float* convt_b = (const float*)d_in[3];
    const float* kp_in_w = (const float*)d_in[4];
    const float* kp_in_b = (const float*)d_in[5];
    const float* rb_w1   = (const float*)d_in[6];
    const float* rb_b1   = (const float*)d_in[7];
    const float* rb_w2   = (const float*)d_in[8];
    const float* rb_b2   = (const float*)d_in[9];
    const float* kern_w  = (const float*)d_in[10];
    const float* kern_b  = (const float*)d_in[11];
    const float* bias_w  = (const float*)d_in[12];
    const float* bias_b  = (const float*)d_in[13];
    const float* lvc_w   = (const float*)d_in[14];
    const float* lvc_b   = (const float*)d_in[15];

    float* wsp = (float*)d_ws;
    float* h_ws     = wsp;                                // B*32*T (replaces old y buffer)
    float* kh_layer = h_ws + (size_t)NB * 32 * T;         // B*256*6144 [b][l][m]
    float* bh       = kh_layer + (size_t)NB * LL * KCL;   // B*256*256
    float* kp_h     = bh + (size_t)NB * 256 * LL;         // B*64*256

    // h ping-pong: layer i reads hbuf[i&1? ...]; final layer writes d_out
    float* h0 = (float*)d_out;
    float* h1 = h_ws;

    // 1) conv transpose into h0 (d_out)
    convt_kernel<<<dim3(33, 4, NB), 256, 0, stream>>>(hidden, convt_w, convt_b, h0);

    // 2) fused kernel-predictor trunk + bias head
    trunk_fused<<<dim3(8, NB), 512, 0, stream>>>(spec, kp_in_w, kp_in_b,
                                                 rb_w1, rb_b1, rb_w2, rb_b2,
                                                 bias_w, bias_b, kp_h, bh);

    static const int dil[4] = {1, 3, 9, 27};
    float* hin = h0;
    float* hout = h1;
    for (int layer = 0; layer < 4; ++layer) {
        kern_head<<<dim3(192, NB), 256, 0, stream>>>(kp_h, kern_w, kern_b, kh_layer, layer);
        layer_fused<<<dim3(LL, NB), 512, 0, stream>>>(
            kh_layer, bh, lvc_w + (size_t)layer * 32 * 32 * 3, lvc_b + layer * 32,
            hin, hout, layer, dil[layer]);
        float* tmp = hin; hin = hout; hout = tmp;
    }
    // after 4 swaps, final output was written to h0 (d_out) on layer 3
}

// Round 9
// 723.655 us; speedup vs baseline: 5.1346x; 1.0853x over previous
//
#include <hip/hip_runtime.h>
#include <math.h>

#define NB 4
#define T 65536
#define TIN 8192
#define LL 256
#define KCL 6144   // per-layer kernel channels = 32*64*3

__device__ __forceinline__ float lrelu_f(float v) { return v >= 0.f ? v : 0.2f * v; }

// ---------------- phase1: convt (264 blocks) + trunk (32 blocks) merged ----------------
// grid 296 x 512 threads. bid < 264: convt role; else trunk role.
union Phase1LDS {
    struct { float xs[32][264]; float wm[64][128]; } cvt;            // 65.8 KB
    struct { float hs[64][56]; float xsp[20][56]; float wt[192][68]; } trk; // 71.0 KB
};

__global__ void __launch_bounds__(512) phase1(
    const float* __restrict__ x, const float* __restrict__ cw,
    const float* __restrict__ cbias, float* __restrict__ hout,
    const float* __restrict__ spec,
    const float* __restrict__ kp_in_w, const float* __restrict__ kp_in_b,
    const float* __restrict__ rb_w1, const float* __restrict__ rb_b1,
    const float* __restrict__ rb_w2, const float* __restrict__ rb_b2,
    float* __restrict__ kp_h) {
    __shared__ Phase1LDS u;
    const int bid = blockIdx.x;
    const int tid = threadIdx.x;
    const int lane = tid & 63, wv = tid >> 6;

    if (bid < 264) {
        // ================= convt role =================
        // out[b,o,t] = bias[o] + sum_i x[b,i,s0]*w[i,o,k0] + x[b,i,s0-1]*w[i,o,k0+8]
        const int bx = bid % 33;
        const int rr = bid / 33;
        const int mtp = rr & 1;          // o half: 0 -> o 0..15, 1 -> o 16..31
        const int b = rr >> 1;
        const int s0base = bx * 256;
        float (*xs)[264] = u.cvt.xs;
        float (*wm)[128] = u.cvt.wm;

        const float* xb = x + (size_t)b * 32 * TIN;
        for (int idx = tid; idx < 32 * 64; idx += 512) {
            int c = idx >> 6, q = idx & 63;
            int p = s0base + q * 4;
            float4 v = (p + 3 < TIN) ? *(const float4*)(xb + c * TIN + p)
                                     : make_float4(0.f, 0.f, 0.f, 0.f);
            *(float4*)&xs[c][4 + 4 * q] = v;
        }
        if (tid < 32) {
            int p = s0base - 1;
            xs[tid][3] = (p >= 0) ? xb[tid * TIN + p] : 0.f;
        }
        for (int idx = tid; idx < 8192; idx += 512) {
            int i = idx >> 7, mm = idx & 127;
            int oo = mtp * 16 + (mm >> 3), k0 = mm & 7;
            wm[i][mm] = (i < 32) ? cw[i * 512 + oo * 16 + k0]
                                 : cw[(i - 32) * 512 + oo * 16 + k0 + 8];
        }
        __syncthreads();

        float acc[2][8][4];   // [ol][k0][si]
#pragma unroll
        for (int ol = 0; ol < 2; ++ol) {
            float bo = cbias[mtp * 16 + wv * 2 + ol];
#pragma unroll
            for (int k0 = 0; k0 < 8; ++k0)
#pragma unroll
                for (int si = 0; si < 4; ++si) acc[ol][k0][si] = bo;
        }

        for (int c = 0; c < 32; ++c) {
            float xm1[4], x0[4];
#pragma unroll
            for (int si = 0; si < 4; ++si) {
                xm1[si] = xs[c][lane + si * 64 + 3];
                x0[si]  = xs[c][lane + si * 64 + 4];
            }
            float w0[16], w1[16];
#pragma unroll
            for (int q = 0; q < 4; ++q) {
                *(float4*)&w0[q * 4] = *(const float4*)&wm[c][wv * 16 + q * 4];
                *(float4*)&w1[q * 4] = *(const float4*)&wm[32 + c][wv * 16 + q * 4];
            }
#pragma unroll
            for (int ol = 0; ol < 2; ++ol)
#pragma unroll
                for (int k0 = 0; k0 < 8; ++k0)
#pragma unroll
                    for (int si = 0; si < 4; ++si)
                        acc[ol][k0][si] += x0[si] * w0[ol * 8 + k0] + xm1[si] * w1[ol * 8 + k0];
        }

#pragma unroll
        for (int ol = 0; ol < 2; ++ol) {
            float* ob = hout + ((size_t)b * 32 + mtp * 16 + wv * 2 + ol) * T;
#pragma unroll
            for (int si = 0; si < 4; ++si) {
                int tb = (s0base + lane + si * 64) * 8 - 4;
                if (tb >= 0 && tb < T)
                    *(float4*)(ob + tb) = make_float4(acc[ol][0][si], acc[ol][1][si],
                                                      acc[ol][2][si], acc[ol][3][si]);
                if (tb + 4 >= 0 && tb + 4 < T)
                    *(float4*)(ob + tb + 4) = make_float4(acc[ol][4][si], acc[ol][5][si],
                                                          acc[ol][6][si], acc[ol][7][si]);
            }
        }
        return;
    }

    // ================= trunk role =================
    const int tb = bid - 264;
    const int lq = tb & 7, b = tb >> 3;
    const int j = lane;
    const int oc0 = wv * 8;
    const int l0 = lq * 32;
    const int labs = l0 - 9 + j;
    const bool lvalid = (labs >= 0 && labs < 256);

    float (*hs)[56] = u.trk.hs;
    float (*xsp)[56] = u.trk.xsp;
    float (*wt)[68] = u.trk.wt;

    float pw[24];
    float px[3];

    auto pf_kpin = [&](int cc) {
#pragma unroll
        for (int t = 0; t < 13; ++t) {
            int idx = t * 512 + tid;
            pw[t] = 0.f;
            if (idx < 6400) pw[t] = kp_in_w[(size_t)(idx / 100) * 500 + cc * 100 + (idx % 100)];
        }
    };
    auto wr_kpin = [&]() {
#pragma unroll
        for (int t = 0; t < 13; ++t) {
            int idx = t * 512 + tid;
            if (idx < 6400) wt[idx % 100][idx / 100] = pw[t];
        }
    };
    auto pf_xsp = [&](int cc) {
#pragma unroll
        for (int t = 0; t < 3; ++t) {
            int idx = t * 512 + tid;
            px[t] = 0.f;
            if (idx < 1120) {
                int c = idx / 56, jj = idx - c * 56;
                int l = l0 - 9 + jj;
                if (l >= 0 && l < 256)
                    px[t] = spec[((size_t)b * 100 + cc * 20 + c) * LL + l];
            }
        }
    };
    auto wr_xsp = [&]() {
#pragma unroll
        for (int t = 0; t < 3; ++t) {
            int idx = t * 512 + tid;
            if (idx < 1120) xsp[idx / 56][idx % 56] = px[t];
        }
    };
    auto pf_w192 = [&](const float* src) {
#pragma unroll
        for (int t = 0; t < 24; ++t) pw[t] = src[t * 512 + tid];
    };
    auto wr_w192 = [&]() {
#pragma unroll
        for (int t = 0; t < 24; ++t) {
            int idx = t * 512 + tid;
            wt[idx % 192][idx / 192] = pw[t];
        }
    };
    auto conv64 = [&](int jlo, int jhi, const float* bptr, float* a) {
#pragma unroll
        for (int oi = 0; oi < 8; ++oi) a[oi] = bptr[oc0 + oi];
        if (j >= jlo && j < jhi) {
            for (int c = 0; c < 64; ++c) {
                float x0 = hs[c][j - 1], x1 = hs[c][j], x2 = hs[c][j + 1];
#pragma unroll
                for (int k = 0; k < 3; ++k) {
                    float xk = (k == 0) ? x0 : (k == 1) ? x1 : x2;
                    float w8[8];
                    *(float4*)&w8[0] = *(const float4*)&wt[c * 3 + k][oc0];
                    *(float4*)&w8[4] = *(const float4*)&wt[c * 3 + k][oc0 + 4];
#pragma unroll
                    for (int oi = 0; oi < 8; ++oi) a[oi] += xk * w8[oi];
                }
            }
        }
    };

    // ---- kp_in: 5 cc pages ----
    pf_kpin(0); pf_xsp(0);
    wr_kpin(); wr_xsp();
    __syncthreads();

    float acc[8];
#pragma unroll
    for (int oi = 0; oi < 8; ++oi) acc[oi] = kp_in_b[oc0 + oi];

    for (int cc = 0; cc < 5; ++cc) {
        if (cc < 4) { pf_kpin(cc + 1); pf_xsp(cc + 1); }
        else        { pf_w192(rb_w1); }
        if (j >= 2 && j < 48) {
            for (int c = 0; c < 20; ++c) {
                float x5[5];
#pragma unroll
                for (int u2 = 0; u2 < 5; ++u2) x5[u2] = xsp[c][j - 2 + u2];
#pragma unroll
                for (int k = 0; k < 5; ++k) {
                    float w8[8];
                    *(float4*)&w8[0] = *(const float4*)&wt[c * 5 + k][oc0];
                    *(float4*)&w8[4] = *(const float4*)&wt[c * 5 + k][oc0 + 4];
#pragma unroll
                    for (int oi = 0; oi < 8; ++oi) acc[oi] += x5[k] * w8[oi];
                }
            }
        }
        if (cc == 4 && j >= 2 && j < 48) {
#pragma unroll
            for (int oi = 0; oi < 8; ++oi) hs[oc0 + oi][j] = lvalid ? acc[oi] : 0.f;
        }
        __syncthreads();
        if (cc < 4) { wr_kpin(); wr_xsp(); }
        else        { wr_w192(); }
        __syncthreads();
    }

    // ---- 3 residual blocks ----
    for (int i = 0; i < 3; ++i) {
        const int jlo1 = 3 + 2 * i, jhi1 = 47 - 2 * i;
        const int jlo2 = jlo1 + 1, jhi2 = jhi1 - 1;
        float r[8];
        if (j >= jlo2 && j < jhi2) {
#pragma unroll
            for (int oi = 0; oi < 8; ++oi) r[oi] = hs[oc0 + oi][j];
        }
        // conv1
        pf_w192(rb_w2 + (size_t)i * 12288);
        float a1[8];
        conv64(jlo1, jhi1, rb_b1 + i * 64, a1);
        __syncthreads();
        if (j >= jlo1 && j < jhi1) {
#pragma unroll
            for (int oi = 0; oi < 8; ++oi) hs[oc0 + oi][j] = lvalid ? lrelu_f(a1[oi]) : 0.f;
        }
        wr_w192();
        __syncthreads();
        // conv2
        if (i < 2) pf_w192(rb_w1 + (size_t)(i + 1) * 12288);
        float a2[8];
        conv64(jlo2, jhi2, rb_b2 + i * 64, a2);
        __syncthreads();
        if (j >= jlo2 && j < jhi2) {
#pragma unroll
            for (int oi = 0; oi < 8; ++oi) hs[oc0 + oi][j] = lvalid ? (lrelu_f(a2[oi]) + r[oi]) : 0.f;
        }
        if (i < 2) wr_w192();
        __syncthreads();
    }

    // ---- write kp_h (central 32 cols) ----
    for (int idx = tid; idx < 64 * 32; idx += 512) {
        int c = idx >> 5, jj = idx & 31;
        kp_h[((size_t)b * 64 + c) * LL + l0 + jj] = hs[c][9 + jj];
    }
}

// ---------------- kern head GEMM (+ bias head blocks at bx>=192 on layer 0) ----------------
__global__ void __launch_bounds__(256, 3) kern_head(const float* __restrict__ kp_h,
                                                    const float* __restrict__ kw,
                                                    const float* __restrict__ kb,
                                                    const float* __restrict__ bias_w,
                                                    const float* __restrict__ bias_b,
                                                    float* __restrict__ kh,
                                                    float* __restrict__ bh, int layer) {
    const int bx = blockIdx.x, b = blockIdx.y;
    const bool isbias = (bx >= 192);
    const int tid = threadIdx.x, lane = tid & 63, wv = tid >> 6;
    __shared__ float xs[32][264];
    __shared__ float ws[96][36];

    int g = 0, oc0 = 0, ci = 0, kk = 0, ocb0 = 0;
    const float* wsrc;
    size_t wrow0;
    int wstride;
    if (!isbias) {
        g = bx >> 1; oc0 = (bx & 1) * 32;
        ci = g / 3; kk = g - ci * 3;
        wsrc = kw + (size_t)layer * KCL * 192;
        wrow0 = (size_t)((ci * 64 + oc0) * 3 + kk) * 192;
        wstride = 576;
    } else {
        ocb0 = (bx - 192) * 32;
        wsrc = bias_w;
        wrow0 = (size_t)ocb0 * 192;
        wstride = 192;
    }

    float acc[8][4];
#pragma unroll
    for (int oi = 0; oi < 8; ++oi) {
        float bv = isbias ? bias_b[ocb0 + wv * 8 + oi]
                          : kb[layer * KCL + (ci * 64 + oc0 + wv * 8 + oi) * 3 + kk];
#pragma unroll
        for (int si = 0; si < 4; ++si) acc[oi][si] = bv;
    }

    for (int half = 0; half < 2; ++half) {
        const int hc0 = half * 32;
        __syncthreads();
        for (int idx = tid; idx < 32 * 64; idx += 256) {
            int c = idx >> 6, q = idx & 63;
            *(float4*)&xs[c][4 + 4 * q] =
                *(const float4*)(kp_h + ((size_t)b * 64 + hc0 + c) * LL + 4 * q);
        }
        if (tid < 32) { xs[tid][3] = 0.f; xs[tid][260] = 0.f; }
        for (int idx = tid; idx < 3072; idx += 256) {
            int ocl = idx / 96, jj = idx - ocl * 96;
            ws[jj][ocl] = wsrc[wrow0 + (size_t)ocl * wstride + hc0 * 3 + jj];
        }
        __syncthreads();
        for (int c = 0; c < 32; ++c) {
#pragma unroll
            for (int t = 0; t < 3; ++t) {
                float wv8[8];
                *(float4*)&wv8[0] = *(const float4*)&ws[c * 3 + t][wv * 8];
                *(float4*)&wv8[4] = *(const float4*)&ws[c * 3 + t][wv * 8 + 4];
                float xv[4];
#pragma unroll
                for (int si = 0; si < 4; ++si) xv[si] = xs[c][lane + si * 64 + t + 3];
#pragma unroll
                for (int oi = 0; oi < 8; ++oi)
#pragma unroll
                    for (int si = 0; si < 4; ++si)
                        acc[oi][si] += wv8[oi] * xv[si];
            }
        }
    }

    if (!isbias) {
#pragma unroll
        for (int si = 0; si < 4; ++si) {
            int l = lane + si * 64;
            float* op = kh + ((size_t)b * LL + l) * KCL + g * 64 + oc0 + wv * 8;
            *(float4*)(op)     = make_float4(acc[0][si], acc[1][si], acc[2][si], acc[3][si]);
            *(float4*)(op + 4) = make_float4(acc[4][si], acc[5][si], acc[6][si], acc[7][si]);
        }
    } else {
#pragma unroll
        for (int oi = 0; oi < 8; ++oi) {
            float* op = bh + ((size_t)b * 256 + ocb0 + wv * 8 + oi) * LL;
#pragma unroll
            for (int si = 0; si < 4; ++si)
                op[lane + si * 64] = acc[oi][si];
        }
    }
}

// ---------------- fused dilated conv + LVC + gate + residual ----------------
__global__ void __launch_bounds__(512, 4) layer_fused(
    const float* __restrict__ kh, const float* __restrict__ bh,
    const float* __restrict__ w, const float* __restrict__ bias,
    const float* __restrict__ hin, float* __restrict__ hout,
    int layer, int dil) {
    const int l = blockIdx.x, b = blockIdx.y;
    const int tid = threadIdx.x, lane = tid & 63, wv = tid >> 6;
    const int t0 = l * 256;
    __shared__ float xh[32][316];   // 40.4 KB
    __shared__ float ks[KCL];       // 24.6 KB
    __shared__ float ws[96][36];    // 13.8 KB

    const float* hb = hin + (size_t)b * 32 * T;
    // interior cols [32,288): aligned float4
    for (int idx = tid; idx < 32 * 64; idx += 512) {
        int c = idx >> 6, q = idx & 63;
        float4 v = *(const float4*)(hb + (size_t)c * T + t0 + 4 * q);
        *(float4*)&xh[c][32 + 4 * q] = make_float4(lrelu_f(v.x), lrelu_f(v.y),
                                                   lrelu_f(v.z), lrelu_f(v.w));
    }
    // halo cols [0,32) and [288,316)
    for (int idx = tid; idx < 32 * 60; idx += 512) {
        int c = idx / 60, r = idx - c * 60;
        int jj = (r < 32) ? r : (256 + r);
        int t = t0 + jj - 32;
        xh[c][jj] = (t >= 0 && t < T) ? lrelu_f(hb[(size_t)c * T + t]) : 0.f;
    }
    {
        const float4* kp = (const float4*)(kh + ((size_t)b * LL + l) * KCL);
        float4* kd = (float4*)ks;
        for (int idx = tid; idx < KCL / 4; idx += 512) kd[idx] = kp[idx];
    }
    for (int idx = tid; idx < 3072; idx += 512) {
        int oc = idx / 96, ck = idx - oc * 96;
        ws[ck][oc] = w[oc * 96 + ck];
    }
    __syncthreads();

    // Phase B: dilated conv -> y regs. wave owns oc4 = wv*4; col = lane + si*64, col<258.
    const int oc4 = wv * 4;
    float yv[5][4];
    {
        float a[5][4];
#pragma unroll
        for (int oi = 0; oi < 4; ++oi) {
            float bv = bias[oc4 + oi];
#pragma unroll
            for (int si = 0; si < 5; ++si) a[si][oi] = bv;
        }
        for (int c = 0; c < 32; ++c) {
#pragma unroll
            for (int k = 0; k < 3; ++k) {
                float4 wq = *(const float4*)&ws[c * 3 + k][oc4];
                float xv[5];
#pragma unroll
                for (int si = 0; si < 5; ++si) {
                    int col = lane + si * 64;
                    int colc = (col < 258) ? col : 257;
                    xv[si] = xh[c][colc + 31 + (k - 1) * dil];
                }
#pragma unroll
                for (int si = 0; si < 5; ++si) {
                    a[si][0] += xv[si] * wq.x;
                    a[si][1] += xv[si] * wq.y;
                    a[si][2] += xv[si] * wq.z;
                    a[si][3] += xv[si] * wq.w;
                }
            }
        }
#pragma unroll
        for (int si = 0; si < 5; ++si) {
            int t = t0 - 1 + lane + si * 64;
            bool tval = (t >= 0 && t < T);
#pragma unroll
            for (int oi = 0; oi < 4; ++oi)
                yv[si][oi] = tval ? lrelu_f(a[si][oi]) : 0.f;
        }
    }
    __syncthreads();

    // Phase C: write y into xh central region
#pragma unroll
    for (int si = 0; si < 5; ++si) {
        int col = lane + si * 64;
        if (col < 258) {
#pragma unroll
            for (int oi = 0; oi < 4; ++oi) xh[oc4 + oi][col + 31] = yv[si][oi];
        }
    }
    __syncthreads();

    // Phase D: LVC
    const int oc8 = (wv & 3) * 8;
    const int sh  = wv >> 2;
    float acc_a[8][2], acc_g[8][2];
#pragma unroll
    for (int oi = 0; oi < 8; ++oi) {
        float ba = bh[((size_t)b * 256 + layer * 64 + oc8 + oi) * LL + l];
        float bg = bh[((size_t)b * 256 + layer * 64 + 32 + oc8 + oi) * LL + l];
#pragma unroll
        for (int si = 0; si < 2; ++si) { acc_a[oi][si] = ba; acc_g[oi][si] = bg; }
    }

    for (int c = 0; c < 32; ++c) {
#pragma unroll
        for (int k = 0; k < 3; ++k) {
            const float* kr = ks + (c * 3 + k) * 64;
            float wa[8], wg[8];
            *(float4*)&wa[0] = *(const float4*)(kr + oc8);
            *(float4*)&wa[4] = *(const float4*)(kr + oc8 + 4);
            *(float4*)&wg[0] = *(const float4*)(kr + 32 + oc8);
            *(float4*)&wg[4] = *(const float4*)(kr + 32 + oc8 + 4);
            float xv2[2];
#pragma unroll
            for (int si = 0; si < 2; ++si) {
                int s = lane + (sh * 2 + si) * 64;
                xv2[si] = xh[c][s + k + 31];
            }
#pragma unroll
            for (int oi = 0; oi < 8; ++oi)
#pragma unroll
                for (int si = 0; si < 2; ++si) {
                    acc_a[oi][si] += wa[oi] * xv2[si];
                    acc_g[oi][si] += wg[oi] * xv2[si];
                }
        }
    }

    // Phase E: gate + residual
#pragma unroll
    for (int oi = 0; oi < 8; ++oi) {
        const float* hip = hin + ((size_t)b * 32 + oc8 + oi) * T + t0;
        float* hop = hout + ((size_t)b * 32 + oc8 + oi) * T + t0;
#pragma unroll
        for (int si = 0; si < 2; ++si) {
            int s = lane + (sh * 2 + si) * 64;
            float a = acc_a[oi][si], g = acc_g[oi][si];
            float sg = 1.f / (1.f + __expf(-a));
            float th = tanhf(g);
            hop[s] = sg * th + hip[s];
        }
    }
}

extern "C" void kernel_launch(void* const* d_in, const int* in_sizes, int n_in,
                              void* d_out, int out_size, void* d_ws, size_t ws_size,
                              hipStream_t stream) {
    const float* hidden  = (const float*)d_in[0];
    const float* spec    = (const float*)d_in[1];
    const float* convt_w = (const float*)d_in[2];
    const float* convt_b = (const float*)d_in[3];
    const float* kp_in_w = (const float*)d_in[4];
    const float* kp_in_b = (const float*)d_in[5];
    const float* rb_w1   = (const float*)d_in[6];
    const float* rb_b1   = (const float*)d_in[7];
    const float* rb_w2   = (const float*)d_in[8];
    const float* rb_b2   = (const float*)d_in[9];
    const float* kern_w  = (const float*)d_in[10];
    const float* kern_b  = (const float*)d_in[11];
    const float* bias_w  = (const float*)d_in[12];
    const float* bias_b  = (const float*)d_in[13];
    const float* lvc_w   = (const float*)d_in[14];
    const float* lvc_b   = (const float*)d_in[15];

    float* wsp = (float*)d_ws;
    float* h_ws     = wsp;                                // B*32*T
    float* kh_layer = h_ws + (size_t)NB * 32 * T;         // B*256*6144 [b][l][m]
    float* bh       = kh_layer + (size_t)NB * LL * KCL;   // B*256*256
    float* kp_h     = bh + (size_t)NB * 256 * LL;         // B*64*256

    float* h0 = (float*)d_out;
    float* h1 = h_ws;

    // 1) merged convt + trunk
    phase1<<<dim3(296), 512, 0, stream>>>(hidden, convt_w, convt_b, h0,
                                          spec, kp_in_w, kp_in_b,
                                          rb_w1, rb_b1, rb_w2, rb_b2, kp_h);

    static const int dil[4] = {1, 3, 9, 27};
    float* hin = h0;
    float* hout = h1;
    for (int layer = 0; layer < 4; ++layer) {
        kern_head<<<dim3(layer == 0 ? 200 : 192, NB), 256, 0, stream>>>(
            kp_h, kern_w, kern_b, bias_w, bias_b, kh_layer, bh, layer);
        layer_fused<<<dim3(LL, NB), 512, 0, stream>>>(
            kh_layer, bh, lvc_w + (size_t)layer * 32 * 32 * 3, lvc_b + layer * 32,
            hin, hout, layer, dil[layer]);
        float* tmp = hin; hin = hout; hout = tmp;
    }
    // after 4 swaps the final output landed in h0 = d_out
}